// Round 1
// baseline (9162.947 us; speedup 1.0000x reference)
//
#include <hip/hip_runtime.h>
#include <hip/hip_bf16.h>
#include <math.h>

// Problem constants: x (2,255,255,128) fp32
constexpr int BSZ = 2;
constexpr int LL  = 255;
constexpr int WW  = 255;
constexpr int DD  = 128;
constexpr int RR  = BSZ * LL;     // 510 rows
constexpr int GG  = RR * WW;      // 130050 positions
constexpr int CH  = 85;           // rows per chunk
constexpr int NCH = 6;            // 6*85 = 510
constexpr int NLOC = CH * WW;     // 21675 positions per chunk

__device__ __forceinline__ float clip1k(float v){ return fminf(fmaxf(v, -1000.f), 1000.f); }
__device__ __forceinline__ float clipT(float v){ return fminf(fmaxf(v, -10000.f), 10000.f); }

// ---------------- tables: sin/cos rotary table (double precision) + row_valid -------------
__global__ __launch_bounds__(256) void k_tables(const int* __restrict__ mask,
                                                float* __restrict__ sintab,
                                                float* __restrict__ costab,
                                                float* __restrict__ rv)
{
    int tid = threadIdx.x;
    for (int idx = tid; idx < WW * 64; idx += 256) {
        int p = idx >> 6, t = idx & 63;
        double freq = exp((double)t * (-9.210340371976184 / 64.0)); // 10000^(-t/64)
        double a = (double)p * freq;
        sintab[idx] = (float)sin(a);
        costab[idx] = (float)cos(a);
    }
    for (int r = tid; r < RR; r += 256) {
        const int* mr = mask + r * WW;
        int s = 0;
        for (int j = 0; j < WW; j++) s += mr[j];
        rv[r] = (s != WW) ? 1.f : 0.f;
    }
}

// ---------------- QKV projection (+clip, +rotary) for one chunk of rows -------------------
// BRANCH 0: horizontal (contiguous rows). BRANCH 1: vertical (gathered).
template <int BRANCH>
__global__ __launch_bounds__(256) void k_qkv(const float* __restrict__ x,
                                             const float* __restrict__ pe,
                                             const float* __restrict__ Wqkv,
                                             const float* __restrict__ bqkv,
                                             const float* __restrict__ sintab,
                                             const float* __restrict__ costab,
                                             float* __restrict__ Qo,
                                             float* __restrict__ Ko,
                                             float* __restrict__ Vo,
                                             int r0)
{
    __shared__ float s[64][128];   // 64 positions, clip+pos-embed applied
    const int tid = threadIdx.x;
    const int g0 = r0 * WW;
    const int base = blockIdx.x * 64;

    // stage 64 positions x 128 channels
    for (int k = 0; k < 8; k++) {
        int i4 = tid + k * 256;
        int pp = i4 >> 5, c4 = i4 & 31;
        int lp = base + pp;
        float4 v = make_float4(0.f, 0.f, 0.f, 0.f);
        if (lp < NLOC) {
            int g = g0 + lp;
            int j = g % WW;
            const float* src;
            int pidx;
            if (BRANCH == 0) {
                src = x + (size_t)g * DD + c4 * 4;
                pidx = (j < 127) ? 0 : 1;
            } else {
                int b = g / (LL * WW);
                int rem = g - b * (LL * WW);
                int i = rem / WW;
                int ri = (i + j + 128) % 255;
                int cj = 254 - j;
                src = x + (size_t)((b * LL + ri) * WW + cj) * DD + c4 * 4;
                pidx = (j <= 127) ? 1 : 0;
            }
            float4 xv = *(const float4*)src;
            float4 pv = *(const float4*)(pe + pidx * DD + c4 * 4);
            v.x = clip1k(xv.x) + pv.x;
            v.y = clip1k(xv.y) + pv.y;
            v.z = clip1k(xv.z) + pv.z;
            v.w = clip1k(xv.w) + pv.w;
        }
        *(float4*)(&s[pp][c4 * 4]) = v;
    }
    __syncthreads();

    if (tid < 192) {
        const int m = tid >> 6;      // 0=Q 1=K 2=V
        const int t = tid & 63;      // pair index
        const int o = m * 128 + 2 * t;
        const float4* w0 = (const float4*)(Wqkv + (size_t)o * DD);
        const float4* w1 = w0 + 32;  // next row
        const float b0 = bqkv[o], b1 = bqkv[o + 1];
        float* dst = (m == 0) ? Qo : ((m == 1) ? Ko : Vo);

        for (int c8 = 0; c8 < 8; c8++) {
            float a0[8], a1[8];
            #pragma unroll
            for (int p = 0; p < 8; p++) { a0[p] = b0; a1[p] = b1; }
            for (int c4 = 0; c4 < 32; c4++) {
                float4 wv0 = w0[c4];
                float4 wv1 = w1[c4];
                #pragma unroll
                for (int p = 0; p < 8; p++) {
                    float4 sv = *(const float4*)(&s[c8 * 8 + p][c4 * 4]);
                    a0[p] += sv.x * wv0.x + sv.y * wv0.y + sv.z * wv0.z + sv.w * wv0.w;
                    a1[p] += sv.x * wv1.x + sv.y * wv1.y + sv.z * wv1.z + sv.w * wv1.w;
                }
            }
            #pragma unroll
            for (int p = 0; p < 8; p++) {
                int lp = base + c8 * 8 + p;
                if (lp >= NLOC) continue;
                int g = g0 + lp;
                int j = g % WW;
                float v0 = clipT(a0[p]);
                float v1 = clipT(a1[p]);
                float r0v, r1v;
                if (m < 2) {
                    float cs = costab[j * 64 + t];
                    float sn = sintab[j * 64 + t];
                    r0v = v0 * cs - v1 * sn;
                    r1v = v1 * cs + v0 * sn;
                } else { r0v = v0; r1v = v1; }
                float2 st = make_float2(r0v, r1v);
                *(float2*)(&dst[(size_t)lp * DD + 2 * t]) = st;
            }
        }
    }
}

// ---------------- attention over one chunk: Q tiles of 32, K/V tiles of 16 ----------------
__global__ __launch_bounds__(256) void k_attn(const float* __restrict__ Q,
                                              const float* __restrict__ K,
                                              const float* __restrict__ V,
                                              const int* __restrict__ mask,
                                              float* __restrict__ out,
                                              int r0)
{
    __shared__ float qs[32][132];
    __shared__ float ks[16][132];
    __shared__ float lg[32][258];
    const int tid = threadIdx.x;
    const int lr = blockIdx.y;           // local row 0..84
    const int rg = r0 + lr;              // global row
    const int q0 = blockIdx.x * 32;
    const int qn = min(32, WW - q0);
    const int mbase = rg * WW;
    const float iscale = 0.0883883476483184f; // 1/sqrt(128)

    // load Q tile
    for (int k = 0; k < 4; k++) {
        int i4 = tid + k * 256;
        int pp = i4 >> 5, c4 = i4 & 31;
        float4 v = make_float4(0.f, 0.f, 0.f, 0.f);
        if (pp < qn) v = *(const float4*)(Q + (size_t)(lr * WW + q0 + pp) * DD + c4 * 4);
        *(float4*)(&qs[pp][c4 * 4]) = v;
    }
    __syncthreads();

    const int qrow = tid >> 3;   // 0..31
    const int l8 = tid & 7;

    // pass A: logits
    for (int kt = 0; kt < 16; kt++) {
        int k0 = kt * 16;
        int kn = min(16, WW - k0);
        for (int k = 0; k < 2; k++) {
            int i4 = tid + k * 256;
            int pp = i4 >> 5, c4 = i4 & 31;
            float4 v = make_float4(0.f, 0.f, 0.f, 0.f);
            if (pp < kn) v = *(const float4*)(K + (size_t)(lr * WW + k0 + pp) * DD + c4 * 4);
            *(float4*)(&ks[pp][c4 * 4]) = v;
        }
        __syncthreads();
        #pragma unroll
        for (int it = 0; it < 2; it++) {
            int kk = l8 + 8 * it;
            float acc = 0.f;
            const float4* qv4 = (const float4*)(&qs[qrow][0]);
            const float4* kv4 = (const float4*)(&ks[kk][0]);
            #pragma unroll 8
            for (int c4 = 0; c4 < 32; c4++) {
                float4 a = qv4[c4], b = kv4[c4];
                acc += a.x * b.x + a.y * b.y + a.z * b.z + a.w * b.w;
            }
            int j = k0 + kk;
            if (kk < kn) {
                float l = clipT(acc * iscale);
                if (mask[mbase + j] > 0) l -= 10000.f;
                lg[qrow][j] = l;
            }
        }
        __syncthreads();
    }

    // pass B: softmax (8 lanes per q row) + post-softmax mask zeroing
    if (qrow < qn) {
        float m = -3.0e38f;
        for (int j = l8; j < WW; j += 8) m = fmaxf(m, lg[qrow][j]);
        m = fmaxf(m, __shfl_xor(m, 1));
        m = fmaxf(m, __shfl_xor(m, 2));
        m = fmaxf(m, __shfl_xor(m, 4));
        float ssum = 0.f;
        for (int j = l8; j < WW; j += 8) ssum += expf(lg[qrow][j] - m);
        ssum += __shfl_xor(ssum, 1);
        ssum += __shfl_xor(ssum, 2);
        ssum += __shfl_xor(ssum, 4);
        float inv = 1.f / ssum;
        for (int j = l8; j < WW; j += 8) {
            float wv = (mask[mbase + j] > 0) ? 0.f : expf(lg[qrow][j] - m) * inv;
            lg[qrow][j] = wv;
        }
    }
    __syncthreads();

    // pass C: AV
    float4 acc[4];
    #pragma unroll
    for (int i = 0; i < 4; i++) acc[i] = make_float4(0.f, 0.f, 0.f, 0.f);
    const int dg = l8;
    for (int kt = 0; kt < 16; kt++) {
        int k0 = kt * 16;
        int kn = min(16, WW - k0);
        for (int k = 0; k < 2; k++) {
            int i4 = tid + k * 256;
            int pp = i4 >> 5, c4 = i4 & 31;
            float4 v = make_float4(0.f, 0.f, 0.f, 0.f);
            if (pp < kn) v = *(const float4*)(V + (size_t)(lr * WW + k0 + pp) * DD + c4 * 4);
            *(float4*)(&ks[pp][c4 * 4]) = v;
        }
        __syncthreads();
        for (int kk = 0; kk < kn; kk++) {
            float wv = lg[qrow][k0 + kk];
            const float4* vr = (const float4*)(&ks[kk][0]);
            #pragma unroll
            for (int i = 0; i < 4; i++) {
                float4 vv = vr[dg + 8 * i];
                acc[i].x += wv * vv.x;
                acc[i].y += wv * vv.y;
                acc[i].z += wv * vv.z;
                acc[i].w += wv * vv.w;
            }
        }
        __syncthreads();
    }
    if (qrow < qn) {
        float* dst = out + (size_t)(rg * WW + q0 + qrow) * DD;
        #pragma unroll
        for (int i = 0; i < 4; i++) *(float4*)(dst + (dg + 8 * i) * 4) = acc[i];
    }
}

// ---------------- dense (concat 256 -> 128) + row_valid + residual + LN1 ------------------
__global__ __launch_bounds__(128) void k_dense_ln1(const float* __restrict__ hv,
                                                   const float* __restrict__ vv,
                                                   const float* __restrict__ dw,
                                                   const float* __restrict__ db,
                                                   const float* __restrict__ x,
                                                   const float* __restrict__ pe,
                                                   const float* __restrict__ rv,
                                                   const float* __restrict__ g1,
                                                   const float* __restrict__ b1,
                                                   float* __restrict__ vout)
{
    __shared__ float cat[16][256];
    __shared__ float val[16][132];
    const int tid = threadIdx.x;
    const int P0 = blockIdx.x * 16;
    const int np = min(16, GG - P0);

    for (int k = 0; k < 8; k++) {
        int i4 = tid + k * 128;
        int p = i4 >> 6, c4 = i4 & 63;
        if (p < np) {
            float4 v;
            if (c4 < 32) v = *(const float4*)(hv + (size_t)(P0 + p) * DD + c4 * 4);
            else         v = *(const float4*)(vv + (size_t)(P0 + p) * DD + (c4 - 32) * 4);
            *(float4*)(&cat[p][c4 * 4]) = v;
        }
    }
    __syncthreads();

    const int o = tid;
    float acc[16];
    float bias = db[o];
    #pragma unroll
    for (int p = 0; p < 16; p++) acc[p] = bias;
    const float4* w4 = (const float4*)(dw + (size_t)o * 256);
    for (int c4 = 0; c4 < 64; c4++) {
        float4 wv = w4[c4];
        #pragma unroll
        for (int p = 0; p < 16; p++) {
            float4 cv = *(const float4*)(&cat[p][c4 * 4]);
            acc[p] += cv.x * wv.x + cv.y * wv.y + cv.z * wv.z + cv.w * wv.w;
        }
    }
    for (int p = 0; p < np; p++) {
        int g = P0 + p;
        int r = g / WW;
        int j = g - r * WW;
        float resid = clip1k(x[(size_t)g * DD + o]) + pe[((j < 127) ? 0 : 1) * DD + o];
        val[p][o] = acc[p] * rv[r] + resid;
    }
    __syncthreads();

    const int p2 = tid >> 3;
    const int l8 = tid & 7;
    if (p2 < np) {
        float s = 0.f;
        for (int i = 0; i < 16; i++) s += val[p2][l8 + 8 * i];
        s += __shfl_xor(s, 1); s += __shfl_xor(s, 2); s += __shfl_xor(s, 4);
        float mu = s * (1.f / 128.f);
        float s2 = 0.f;
        for (int i = 0; i < 16; i++) { float d = val[p2][l8 + 8 * i] - mu; s2 += d * d; }
        s2 += __shfl_xor(s2, 1); s2 += __shfl_xor(s2, 2); s2 += __shfl_xor(s2, 4);
        float inv = rsqrtf(s2 * (1.f / 128.f) + 1e-5f);
        for (int i = 0; i < 16; i++) {
            int oc = l8 + 8 * i;
            val[p2][oc] = (val[p2][oc] - mu) * inv * g1[oc] + b1[oc];
        }
    }
    __syncthreads();
    for (int k = 0; k < 4; k++) {
        int i4 = tid + k * 128;
        int p = i4 >> 5, c4 = i4 & 31;
        if (p < np) *(float4*)(vout + (size_t)(P0 + p) * DD + c4 * 4) = *(const float4*)(&val[p][c4 * 4]);
    }
}

// ---------------- masked 3x3 conv (NHWC), 8 output columns per block ----------------------
__global__ __launch_bounds__(256) void k_conv1(const float* __restrict__ vb,
                                               const int* __restrict__ mask,
                                               const float* __restrict__ w1,
                                               float* __restrict__ c1)
{
    __shared__ float sN[3][10][128];
    const int tid = threadIdx.x;
    const int r = blockIdx.y;
    const int b = r / LL, i = r - (r / LL) * LL;
    const int j0 = blockIdx.x * 8;

    for (int k = 0; k < 4; k++) {
        int i4 = tid + k * 256;
        if (i4 < 960) {
            int rowi = i4 / 320;
            int rem = i4 - rowi * 320;
            int col = rem >> 5, c4 = rem & 31;
            int ni = i + rowi - 1, nj = j0 + col - 1;
            float4 v = make_float4(0.f, 0.f, 0.f, 0.f);
            if (ni >= 0 && ni < LL && nj >= 0 && nj < WW) {
                int gp = (b * LL + ni) * WW + nj;
                if (mask[gp] == 0) v = *(const float4*)(vb + (size_t)gp * DD + c4 * 4);
            }
            *(float4*)(&sN[rowi][col][c4 * 4]) = v;
        }
    }
    __syncthreads();

    const int o = tid & 127;
    const int half = tid >> 7;
    float acc[4] = {0.f, 0.f, 0.f, 0.f};
    const float* wo = w1 + (size_t)o * 1152;
    for (int c = 0; c < 128; c++) {
        float sreg[3][6];
        #pragma unroll
        for (int rr = 0; rr < 3; rr++)
            #pragma unroll
            for (int cc = 0; cc < 6; cc++)
                sreg[rr][cc] = sN[rr][half * 4 + cc][c];
        const float* wc = wo + c * 9;
        #pragma unroll
        for (int ky = 0; ky < 3; ky++) {
            #pragma unroll
            for (int kx = 0; kx < 3; kx++) {
                float wv = wc[ky * 3 + kx];
                #pragma unroll
                for (int jj = 0; jj < 4; jj++)
                    acc[jj] += wv * sreg[ky][jj + kx];
            }
        }
    }
    #pragma unroll
    for (int jj = 0; jj < 4; jj++) {
        int j = j0 + half * 4 + jj;
        if (j < WW) {
            float a = acc[jj];
            float y = 0.5f * a * (1.f + erff(a * 0.70710678118654752f)); // exact GELU
            c1[(size_t)((b * LL + i) * WW + j) * DD + o] = y;
        }
    }
}

__global__ __launch_bounds__(256) void k_conv2(const float* __restrict__ c1,
                                               const int* __restrict__ mask,
                                               const float* __restrict__ w2,
                                               const float* __restrict__ vb,
                                               const float* __restrict__ g2,
                                               const float* __restrict__ b2,
                                               float* __restrict__ out)
{
    __shared__ float sN[3][10][128];
    __shared__ float red[4], red2[4];
    const int tid = threadIdx.x;
    const int r = blockIdx.y;
    const int b = r / LL, i = r - (r / LL) * LL;
    const int j0 = blockIdx.x * 8;

    for (int k = 0; k < 4; k++) {
        int i4 = tid + k * 256;
        if (i4 < 960) {
            int rowi = i4 / 320;
            int rem = i4 - rowi * 320;
            int col = rem >> 5, c4 = rem & 31;
            int ni = i + rowi - 1, nj = j0 + col - 1;
            float4 v = make_float4(0.f, 0.f, 0.f, 0.f);
            if (ni >= 0 && ni < LL && nj >= 0 && nj < WW) {
                int gp = (b * LL + ni) * WW + nj;
                if (mask[gp] == 0) v = *(const float4*)(c1 + (size_t)gp * DD + c4 * 4);
            }
            *(float4*)(&sN[rowi][col][c4 * 4]) = v;
        }
    }
    __syncthreads();

    const int o = tid & 127;
    const int half = tid >> 7;
    float acc[4] = {0.f, 0.f, 0.f, 0.f};
    const float* wo = w2 + (size_t)o * 1152;
    for (int c = 0; c < 128; c++) {
        float sreg[3][6];
        #pragma unroll
        for (int rr = 0; rr < 3; rr++)
            #pragma unroll
            for (int cc = 0; cc < 6; cc++)
                sreg[rr][cc] = sN[rr][half * 4 + cc][c];
        const float* wc = wo + c * 9;
        #pragma unroll
        for (int ky = 0; ky < 3; ky++) {
            #pragma unroll
            for (int kx = 0; kx < 3; kx++) {
                float wv = wc[ky * 3 + kx];
                #pragma unroll
                for (int jj = 0; jj < 4; jj++)
                    acc[jj] += wv * sreg[ky][jj + kx];
            }
        }
    }

    const int wv64 = tid >> 6;
    for (int jj = 0; jj < 4; jj++) {
        int j = j0 + half * 4 + jj;
        bool valid = (j < WW);
        float xv = 0.f;
        size_t gpos = 0;
        if (valid) {
            gpos = (size_t)((b * LL + i) * WW + j) * DD + o;
            xv = acc[jj] + vb[gpos];
        }
        float s = xv;
        #pragma unroll
        for (int off = 32; off > 0; off >>= 1) s += __shfl_xor(s, off);
        if ((tid & 63) == 0) red[wv64] = s;
        __syncthreads();
        float mu = (red[half * 2] + red[half * 2 + 1]) * (1.f / 128.f);
        float d = xv - mu;
        float s2 = d * d;
        #pragma unroll
        for (int off = 32; off > 0; off >>= 1) s2 += __shfl_xor(s2, off);
        if ((tid & 63) == 0) red2[wv64] = s2;
        __syncthreads();
        float var = (red2[half * 2] + red2[half * 2 + 1]) * (1.f / 128.f);
        if (valid) out[gpos] = d * rsqrtf(var + 1e-5f) * g2[o] + b2[o];
        __syncthreads();
    }
}

extern "C" void kernel_launch(void* const* d_in, const int* in_sizes, int n_in,
                              void* d_out, int out_size, void* d_ws, size_t ws_size,
                              hipStream_t stream)
{
    (void)in_sizes; (void)n_in; (void)out_size; (void)ws_size;
    const float* x    = (const float*)d_in[0];
    const int*   mask = (const int*)d_in[1];
    const float* pe   = (const float*)d_in[2];
    const float* hW   = (const float*)d_in[3];
    const float* hb   = (const float*)d_in[4];
    const float* vW   = (const float*)d_in[5];
    const float* vbias= (const float*)d_in[6];
    const float* dw   = (const float*)d_in[7];
    const float* db   = (const float*)d_in[8];
    const float* g1   = (const float*)d_in[9];
    const float* b1   = (const float*)d_in[10];
    const float* w1   = (const float*)d_in[11];
    const float* w2   = (const float*)d_in[12];
    const float* g2   = (const float*)d_in[13];
    const float* b2   = (const float*)d_in[14];
    float* out = (float*)d_out;

    // workspace layout (needs ~192 MiB)
    char* ws = (char*)d_ws;
    float* sintab = (float*)ws;                 // 255*64
    float* costab = sintab + 16384;
    float* rvbuf  = costab + 16384;             // 510
    float* A  = (float*)(ws + (1u << 20));      // h_v, later c1 (16,646,400 floats)
    float* Bb = A + 16646400;                   // v_v
    float* C  = Bb + 16646400;                  // QKV chunk, later v (LN1 output)
    float* Qc = C;
    float* Kc = C + 2774400;                    // 85*255*128
    float* Vc = C + 5548800;

    k_tables<<<1, 256, 0, stream>>>(mask, sintab, costab, rvbuf);
    for (int ch = 0; ch < NCH; ch++) {
        int r0 = ch * CH;
        k_qkv<0><<<339, 256, 0, stream>>>(x, pe, hW, hb, sintab, costab, Qc, Kc, Vc, r0);
        k_attn<<<dim3(8, CH), 256, 0, stream>>>(Qc, Kc, Vc, mask, A, r0);
        k_qkv<1><<<339, 256, 0, stream>>>(x, pe, vW, vbias, sintab, costab, Qc, Kc, Vc, r0);
        k_attn<<<dim3(8, CH), 256, 0, stream>>>(Qc, Kc, Vc, mask, Bb, r0);
    }
    k_dense_ln1<<<8129, 128, 0, stream>>>(A, Bb, dw, db, x, pe, rvbuf, g1, b1, C);
    k_conv1<<<dim3(32, RR), 256, 0, stream>>>(C, mask, w1, A);
    k_conv2<<<dim3(32, RR), 256, 0, stream>>>(A, mask, w2, C, g2, b2, out);
}

// Round 2
// 4143.308 us; speedup vs baseline: 2.2115x; 2.2115x over previous
//
#include <hip/hip_runtime.h>
#include <hip/hip_bf16.h>
#include <math.h>

constexpr int BSZ = 2;
constexpr int LL  = 255;
constexpr int WW  = 255;
constexpr int DD  = 128;
constexpr int RR  = BSZ * LL;     // 510 rows
constexpr int GG  = RR * WW;      // 130050 positions
constexpr int CH  = 85;           // rows per chunk
constexpr int NCH = 6;
constexpr int NLOC = CH * WW;

typedef __attribute__((ext_vector_type(8))) short bf16x8;
typedef __attribute__((ext_vector_type(4))) float f32x4;

__device__ __forceinline__ float clip1k(float v){ return fminf(fmaxf(v, -1000.f), 1000.f); }
__device__ __forceinline__ float clipT(float v){ return fminf(fmaxf(v, -10000.f), 10000.f); }
__device__ __forceinline__ unsigned short f2bf(float f){
    unsigned int u = __float_as_uint(f);
    unsigned int r = u + 0x7fffu + ((u >> 16) & 1u);
    return (unsigned short)(r >> 16);
}

// ---------------- tables ------------------------------------------------------------------
__global__ __launch_bounds__(256) void k_tables(const int* __restrict__ mask,
                                                float* __restrict__ sintab,
                                                float* __restrict__ costab,
                                                float* __restrict__ rv)
{
    int tid = threadIdx.x;
    for (int idx = tid; idx < WW * 64; idx += 256) {
        int p = idx >> 6, t = idx & 63;
        double freq = exp((double)t * (-9.210340371976184 / 64.0));
        double a = (double)p * freq;
        sintab[idx] = (float)sin(a);
        costab[idx] = (float)cos(a);
    }
    for (int r = tid; r < RR; r += 256) {
        const int* mr = mask + r * WW;
        int s = 0;
        for (int j = 0; j < WW; j++) s += mr[j];
        rv[r] = (s != WW) ? 1.f : 0.f;
    }
}

// ---------------- conv weight transpose to bf16 [o][ky*384+kx*128+c] ----------------------
__global__ __launch_bounds__(256) void k_wconv(const float* __restrict__ w1,
                                               const float* __restrict__ w2,
                                               unsigned short* __restrict__ Wt1,
                                               unsigned short* __restrict__ Wt2)
{
    int idx = blockIdx.x * 256 + threadIdx.x;
    if (idx >= 2 * 147456) return;
    int buf = idx / 147456, rem = idx % 147456;
    int o = rem / 1152, k = rem % 1152;
    int ky = k / 384, kx = (k % 384) / 128, c = k % 128;
    const float* w = buf ? w2 : w1;
    float v = w[((o * 128 + c) * 3 + ky) * 3 + kx];
    (buf ? Wt2 : Wt1)[rem] = f2bf(v);
}

// ---------------- QKV projection (+clip, +rotary) ------------------------------------------
template <int BRANCH>
__global__ __launch_bounds__(256) void k_qkv(const float* __restrict__ x,
                                             const float* __restrict__ pe,
                                             const float* __restrict__ Wqkv,
                                             const float* __restrict__ bqkv,
                                             const float* __restrict__ sintab,
                                             const float* __restrict__ costab,
                                             float* __restrict__ Qo,
                                             float* __restrict__ Ko,
                                             float* __restrict__ Vo,
                                             int r0)
{
    __shared__ float s[64][128];
    const int tid = threadIdx.x;
    const int g0 = r0 * WW;
    const int base = blockIdx.x * 64;

    for (int k = 0; k < 8; k++) {
        int i4 = tid + k * 256;
        int pp = i4 >> 5, c4 = i4 & 31;
        int lp = base + pp;
        float4 v = make_float4(0.f, 0.f, 0.f, 0.f);
        if (lp < NLOC) {
            int g = g0 + lp;
            int j = g % WW;
            const float* src;
            int pidx;
            if (BRANCH == 0) {
                src = x + (size_t)g * DD + c4 * 4;
                pidx = (j < 127) ? 0 : 1;
            } else {
                int b = g / (LL * WW);
                int rem = g - b * (LL * WW);
                int i = rem / WW;
                int ri = (i + j + 128) % 255;
                int cj = 254 - j;
                src = x + (size_t)((b * LL + ri) * WW + cj) * DD + c4 * 4;
                pidx = (j <= 127) ? 1 : 0;
            }
            float4 xv = *(const float4*)src;
            float4 pv = *(const float4*)(pe + pidx * DD + c4 * 4);
            v.x = clip1k(xv.x) + pv.x;
            v.y = clip1k(xv.y) + pv.y;
            v.z = clip1k(xv.z) + pv.z;
            v.w = clip1k(xv.w) + pv.w;
        }
        *(float4*)(&s[pp][c4 * 4]) = v;
    }
    __syncthreads();

    if (tid < 192) {
        const int m = tid >> 6;
        const int t = tid & 63;
        const int o = m * 128 + 2 * t;
        const float4* w0 = (const float4*)(Wqkv + (size_t)o * DD);
        const float4* w1 = w0 + 32;
        const float b0 = bqkv[o], b1 = bqkv[o + 1];
        float* dst = (m == 0) ? Qo : ((m == 1) ? Ko : Vo);

        for (int c8 = 0; c8 < 8; c8++) {
            float a0[8], a1[8];
            #pragma unroll
            for (int p = 0; p < 8; p++) { a0[p] = b0; a1[p] = b1; }
            for (int c4 = 0; c4 < 32; c4++) {
                float4 wv0 = w0[c4];
                float4 wv1 = w1[c4];
                #pragma unroll
                for (int p = 0; p < 8; p++) {
                    float4 sv = *(const float4*)(&s[c8 * 8 + p][c4 * 4]);
                    a0[p] += sv.x * wv0.x + sv.y * wv0.y + sv.z * wv0.z + sv.w * wv0.w;
                    a1[p] += sv.x * wv1.x + sv.y * wv1.y + sv.z * wv1.z + sv.w * wv1.w;
                }
            }
            #pragma unroll
            for (int p = 0; p < 8; p++) {
                int lp = base + c8 * 8 + p;
                if (lp >= NLOC) continue;
                int g = g0 + lp;
                int j = g % WW;
                float v0 = clipT(a0[p]);
                float v1 = clipT(a1[p]);
                float r0v, r1v;
                if (m < 2) {
                    float cs = costab[j * 64 + t];
                    float sn = sintab[j * 64 + t];
                    r0v = v0 * cs - v1 * sn;
                    r1v = v1 * cs + v0 * sn;
                } else { r0v = v0; r1v = v1; }
                float2 st = make_float2(r0v, r1v);
                *(float2*)(&dst[(size_t)lp * DD + 2 * t]) = st;
            }
        }
    }
}

// ---------------- attention ----------------------------------------------------------------
__global__ __launch_bounds__(256) void k_attn(const float* __restrict__ Q,
                                              const float* __restrict__ K,
                                              const float* __restrict__ V,
                                              const int* __restrict__ mask,
                                              float* __restrict__ out,
                                              int r0)
{
    __shared__ float qs[32][132];
    __shared__ float ks[16][132];
    __shared__ float lg[32][258];
    const int tid = threadIdx.x;
    const int lr = blockIdx.y;
    const int rg = r0 + lr;
    const int q0 = blockIdx.x * 32;
    const int qn = min(32, WW - q0);
    const int mbase = rg * WW;
    const float iscale = 0.0883883476483184f;

    for (int k = 0; k < 4; k++) {
        int i4 = tid + k * 256;
        int pp = i4 >> 5, c4 = i4 & 31;
        float4 v = make_float4(0.f, 0.f, 0.f, 0.f);
        if (pp < qn) v = *(const float4*)(Q + (size_t)(lr * WW + q0 + pp) * DD + c4 * 4);
        *(float4*)(&qs[pp][c4 * 4]) = v;
    }
    __syncthreads();

    const int qrow = tid >> 3;
    const int l8 = tid & 7;

    for (int kt = 0; kt < 16; kt++) {
        int k0 = kt * 16;
        int kn = min(16, WW - k0);
        for (int k = 0; k < 2; k++) {
            int i4 = tid + k * 256;
            int pp = i4 >> 5, c4 = i4 & 31;
            float4 v = make_float4(0.f, 0.f, 0.f, 0.f);
            if (pp < kn) v = *(const float4*)(K + (size_t)(lr * WW + k0 + pp) * DD + c4 * 4);
            *(float4*)(&ks[pp][c4 * 4]) = v;
        }
        __syncthreads();
        #pragma unroll
        for (int it = 0; it < 2; it++) {
            int kk = l8 + 8 * it;
            float acc = 0.f;
            const float4* qv4 = (const float4*)(&qs[qrow][0]);
            const float4* kv4 = (const float4*)(&ks[kk][0]);
            #pragma unroll 8
            for (int c4 = 0; c4 < 32; c4++) {
                float4 a = qv4[c4], b = kv4[c4];
                acc += a.x * b.x + a.y * b.y + a.z * b.z + a.w * b.w;
            }
            int j = k0 + kk;
            if (kk < kn) {
                float l = clipT(acc * iscale);
                if (mask[mbase + j] > 0) l -= 10000.f;
                lg[qrow][j] = l;
            }
        }
        __syncthreads();
    }

    if (qrow < qn) {
        float m = -3.0e38f;
        for (int j = l8; j < WW; j += 8) m = fmaxf(m, lg[qrow][j]);
        m = fmaxf(m, __shfl_xor(m, 1));
        m = fmaxf(m, __shfl_xor(m, 2));
        m = fmaxf(m, __shfl_xor(m, 4));
        float ssum = 0.f;
        for (int j = l8; j < WW; j += 8) ssum += expf(lg[qrow][j] - m);
        ssum += __shfl_xor(ssum, 1);
        ssum += __shfl_xor(ssum, 2);
        ssum += __shfl_xor(ssum, 4);
        float inv = 1.f / ssum;
        for (int j = l8; j < WW; j += 8) {
            float wv = (mask[mbase + j] > 0) ? 0.f : expf(lg[qrow][j] - m) * inv;
            lg[qrow][j] = wv;
        }
    }
    __syncthreads();

    float4 acc[4];
    #pragma unroll
    for (int i = 0; i < 4; i++) acc[i] = make_float4(0.f, 0.f, 0.f, 0.f);
    const int dg = l8;
    for (int kt = 0; kt < 16; kt++) {
        int k0 = kt * 16;
        int kn = min(16, WW - k0);
        for (int k = 0; k < 2; k++) {
            int i4 = tid + k * 256;
            int pp = i4 >> 5, c4 = i4 & 31;
            float4 v = make_float4(0.f, 0.f, 0.f, 0.f);
            if (pp < kn) v = *(const float4*)(V + (size_t)(lr * WW + k0 + pp) * DD + c4 * 4);
            *(float4*)(&ks[pp][c4 * 4]) = v;
        }
        __syncthreads();
        for (int kk = 0; kk < kn; kk++) {
            float wv = lg[qrow][k0 + kk];
            const float4* vr = (const float4*)(&ks[kk][0]);
            #pragma unroll
            for (int i = 0; i < 4; i++) {
                float4 vv = vr[dg + 8 * i];
                acc[i].x += wv * vv.x;
                acc[i].y += wv * vv.y;
                acc[i].z += wv * vv.z;
                acc[i].w += wv * vv.w;
            }
        }
        __syncthreads();
    }
    if (qrow < qn) {
        float* dst = out + (size_t)(rg * WW + q0 + qrow) * DD;
        #pragma unroll
        for (int i = 0; i < 4; i++) *(float4*)(dst + (dg + 8 * i) * 4) = acc[i];
    }
}

// ---------------- dense (concat 256 -> 128) + row_valid + residual + LN1 -------------------
__global__ __launch_bounds__(128) void k_dense_ln1(const float* __restrict__ hv,
                                                   const float* __restrict__ vv,
                                                   const float* __restrict__ dw,
                                                   const float* __restrict__ db,
                                                   const float* __restrict__ x,
                                                   const float* __restrict__ pe,
                                                   const float* __restrict__ rv,
                                                   const float* __restrict__ g1,
                                                   const float* __restrict__ b1,
                                                   float* __restrict__ vout)
{
    __shared__ float cat[16][256];
    __shared__ float val[16][132];
    const int tid = threadIdx.x;
    const int P0 = blockIdx.x * 16;
    const int np = min(16, GG - P0);

    for (int k = 0; k < 8; k++) {
        int i4 = tid + k * 128;
        int p = i4 >> 6, c4 = i4 & 63;
        if (p < np) {
            float4 v;
            if (c4 < 32) v = *(const float4*)(hv + (size_t)(P0 + p) * DD + c4 * 4);
            else         v = *(const float4*)(vv + (size_t)(P0 + p) * DD + (c4 - 32) * 4);
            *(float4*)(&cat[p][c4 * 4]) = v;
        }
    }
    __syncthreads();

    const int o = tid;
    float acc[16];
    float bias = db[o];
    #pragma unroll
    for (int p = 0; p < 16; p++) acc[p] = bias;
    const float4* w4 = (const float4*)(dw + (size_t)o * 256);
    for (int c4 = 0; c4 < 64; c4++) {
        float4 wv = w4[c4];
        #pragma unroll
        for (int p = 0; p < 16; p++) {
            float4 cv = *(const float4*)(&cat[p][c4 * 4]);
            acc[p] += cv.x * wv.x + cv.y * wv.y + cv.z * wv.z + cv.w * wv.w;
        }
    }
    for (int p = 0; p < np; p++) {
        int g = P0 + p;
        int r = g / WW;
        int j = g - r * WW;
        float resid = clip1k(x[(size_t)g * DD + o]) + pe[((j < 127) ? 0 : 1) * DD + o];
        val[p][o] = acc[p] * rv[r] + resid;
    }
    __syncthreads();

    const int p2 = tid >> 3;
    const int l8 = tid & 7;
    if (p2 < np) {
        float s = 0.f;
        for (int i = 0; i < 16; i++) s += val[p2][l8 + 8 * i];
        s += __shfl_xor(s, 1); s += __shfl_xor(s, 2); s += __shfl_xor(s, 4);
        float mu = s * (1.f / 128.f);
        float s2 = 0.f;
        for (int i = 0; i < 16; i++) { float d = val[p2][l8 + 8 * i] - mu; s2 += d * d; }
        s2 += __shfl_xor(s2, 1); s2 += __shfl_xor(s2, 2); s2 += __shfl_xor(s2, 4);
        float inv = rsqrtf(s2 * (1.f / 128.f) + 1e-5f);
        for (int i = 0; i < 16; i++) {
            int oc = l8 + 8 * i;
            val[p2][oc] = (val[p2][oc] - mu) * inv * g1[oc] + b1[oc];
        }
    }
    __syncthreads();
    for (int k = 0; k < 4; k++) {
        int i4 = tid + k * 128;
        int p = i4 >> 5, c4 = i4 & 31;
        if (p < np) *(float4*)(vout + (size_t)(P0 + p) * DD + c4 * 4) = *(const float4*)(&val[p][c4 * 4]);
    }
}

// ---------------- MFMA masked 3x3 conv: block = 128 j x 128 o, 4 waves of 64x64 ------------
// WHICH==1: input fp32 (v), output bf16 gelu (c1). WHICH==2: input bf16 (c1),
// output fp32 = LN2(conv + vb).
template <int WHICH>
__global__ __launch_bounds__(256, 2) void k_convm(const float* __restrict__ inF,
                                                  const unsigned short* __restrict__ inB,
                                                  const int* __restrict__ mask,
                                                  const unsigned short* __restrict__ Wt,
                                                  const float* __restrict__ vb,
                                                  const float* __restrict__ g2,
                                                  const float* __restrict__ b2,
                                                  unsigned short* __restrict__ outB,
                                                  float* __restrict__ outF)
{
    __shared__ unsigned short s_a[132][136];   // input halo row (1 ky at a time), bf16
    __shared__ unsigned short s_b[2][128][40]; // weight k-step tile dbuf, bf16
    __shared__ float redS[128][2], redQ[128][2];

    const int tid = threadIdx.x;
    const int l  = tid & 63, lrn = l & 15, lgp = l >> 4;
    const int w  = tid >> 6, wr = w & 1, wc = w >> 1;
    const int r  = blockIdx.y, b = r / LL, i = r % LL;
    const int j0 = blockIdx.x * 128;

    f32x4 acc[4][4];
    const f32x4 z4 = {0.f, 0.f, 0.f, 0.f};
    #pragma unroll
    for (int jt = 0; jt < 4; jt++)
        #pragma unroll
        for (int ot = 0; ot < 4; ot++) acc[jt][ot] = z4;

    for (int ky = 0; ky < 3; ky++) {
        // stage A halo: 132 cols x 128 ch of input row i+ky-1 (masked, bf16)
        const int ri = i + ky - 1;
        for (int t = tid; t < 132 * 16; t += 256) {
            int col = t >> 4, c8 = t & 15;
            int nj = j0 - 1 + col;
            int4 pk = make_int4(0, 0, 0, 0);
            if (ri >= 0 && ri < LL && nj >= 0 && nj < WW) {
                int mp = (b * LL + ri) * WW + nj;
                if (mask[mp] == 0) {
                    if (WHICH == 1) {
                        const float4* p = (const float4*)(inF + (size_t)mp * DD + c8 * 8);
                        float4 x0 = p[0], x1 = p[1];
                        pk.x = f2bf(x0.x) | (f2bf(x0.y) << 16);
                        pk.y = f2bf(x0.z) | (f2bf(x0.w) << 16);
                        pk.z = f2bf(x1.x) | (f2bf(x1.y) << 16);
                        pk.w = f2bf(x1.z) | (f2bf(x1.w) << 16);
                    } else {
                        pk = *(const int4*)(inB + (size_t)mp * DD + c8 * 8);
                    }
                }
            }
            *(int4*)(&s_a[col][c8 * 8]) = pk;
        }
        // stage B k-step 0 into buf 0
        {
            const int kb = ky * 384;
            #pragma unroll
            for (int it = 0; it < 2; it++) {
                int idx = it * 256 + tid, o = idx >> 2, q = idx & 3;
                *(int4*)(&s_b[0][o][q * 8]) = *(const int4*)(Wt + (size_t)o * 1152 + kb + q * 8);
            }
        }
        __syncthreads();

        for (int s = 0; s < 12; s++) {
            if (s < 11) {
                const int kb = ky * 384 + (s + 1) * 32;
                const int bufn = (s + 1) & 1;
                #pragma unroll
                for (int it = 0; it < 2; it++) {
                    int idx = it * 256 + tid, o = idx >> 2, q = idx & 3;
                    *(int4*)(&s_b[bufn][o][q * 8]) = *(const int4*)(Wt + (size_t)o * 1152 + kb + q * 8);
                }
            }
            const int kx = s >> 2;
            const int c0 = (s & 3) * 32 + lgp * 8;
            const int buf = s & 1;
            bf16x8 af[4], bfr[4];
            #pragma unroll
            for (int jt = 0; jt < 4; jt++) {
                int col = wr * 64 + jt * 16 + lrn + kx;
                af[jt] = *(const bf16x8*)(&s_a[col][c0]);
            }
            #pragma unroll
            for (int ot = 0; ot < 4; ot++) {
                int o = wc * 64 + ot * 16 + lrn;
                bfr[ot] = *(const bf16x8*)(&s_b[buf][o][lgp * 8]);
            }
            #pragma unroll
            for (int jt = 0; jt < 4; jt++)
                #pragma unroll
                for (int ot = 0; ot < 4; ot++)
                    acc[jt][ot] = __builtin_amdgcn_mfma_f32_16x16x32_bf16(af[jt], bfr[ot], acc[jt][ot], 0, 0, 0);
            __syncthreads();
        }
    }

    if (WHICH == 1) {
        // exact GELU, store bf16
        #pragma unroll
        for (int jt = 0; jt < 4; jt++) {
            #pragma unroll
            for (int r4 = 0; r4 < 4; r4++) {
                int jl = wr * 64 + jt * 16 + lgp * 4 + r4;
                int j = j0 + jl;
                if (j >= WW) continue;
                size_t gp = (size_t)((b * LL + i) * WW + j) * DD;
                #pragma unroll
                for (int ot = 0; ot < 4; ot++) {
                    int o = wc * 64 + ot * 16 + lrn;
                    float a = acc[jt][ot][r4];
                    float y = 0.5f * a * (1.f + erff(a * 0.70710678118654752f));
                    outB[gp + o] = f2bf(y);
                }
            }
        }
    } else {
        // residual add + LN2
        float g2v[4], b2v[4];
        #pragma unroll
        for (int ot = 0; ot < 4; ot++) {
            int o = wc * 64 + ot * 16 + lrn;
            g2v[ot] = g2[o]; b2v[ot] = b2[o];
        }
        #pragma unroll
        for (int jt = 0; jt < 4; jt++) {
            #pragma unroll
            for (int r4 = 0; r4 < 4; r4++) {
                int jl = wr * 64 + jt * 16 + lgp * 4 + r4;
                int j = j0 + jl;
                if (j >= WW) continue;
                size_t gp = (size_t)((b * LL + i) * WW + j) * DD;
                #pragma unroll
                for (int ot = 0; ot < 4; ot++) {
                    int o = wc * 64 + ot * 16 + lrn;
                    acc[jt][ot][r4] += vb[gp + o];
                }
            }
        }
        #pragma unroll
        for (int jt = 0; jt < 4; jt++) {
            #pragma unroll
            for (int r4 = 0; r4 < 4; r4++) {
                float s1 = 0.f, s2 = 0.f;
                #pragma unroll
                for (int ot = 0; ot < 4; ot++) {
                    float v = acc[jt][ot][r4];
                    s1 += v; s2 += v * v;
                }
                #pragma unroll
                for (int off = 1; off < 16; off <<= 1) {
                    s1 += __shfl_xor(s1, off);
                    s2 += __shfl_xor(s2, off);
                }
                if (lrn == 0) {
                    int jl = wr * 64 + jt * 16 + lgp * 4 + r4;
                    redS[jl][wc] = s1;
                    redQ[jl][wc] = s2;
                }
            }
        }
        __syncthreads();
        #pragma unroll
        for (int jt = 0; jt < 4; jt++) {
            #pragma unroll
            for (int r4 = 0; r4 < 4; r4++) {
                int jl = wr * 64 + jt * 16 + lgp * 4 + r4;
                int j = j0 + jl;
                if (j >= WW) continue;
                float mu = (redS[jl][0] + redS[jl][1]) * 0.0078125f;
                float q  = (redQ[jl][0] + redQ[jl][1]) * 0.0078125f;
                float inv = rsqrtf(q - mu * mu + 1e-5f);
                size_t gp = (size_t)((b * LL + i) * WW + j) * DD;
                #pragma unroll
                for (int ot = 0; ot < 4; ot++) {
                    int o = wc * 64 + ot * 16 + lrn;
                    outF[gp + o] = (acc[jt][ot][r4] - mu) * inv * g2v[ot] + b2v[ot];
                }
            }
        }
    }
}

extern "C" void kernel_launch(void* const* d_in, const int* in_sizes, int n_in,
                              void* d_out, int out_size, void* d_ws, size_t ws_size,
                              hipStream_t stream)
{
    (void)in_sizes; (void)n_in; (void)out_size; (void)ws_size;
    const float* x    = (const float*)d_in[0];
    const int*   mask = (const int*)d_in[1];
    const float* pe   = (const float*)d_in[2];
    const float* hW   = (const float*)d_in[3];
    const float* hb   = (const float*)d_in[4];
    const float* vW   = (const float*)d_in[5];
    const float* vbias= (const float*)d_in[6];
    const float* dw   = (const float*)d_in[7];
    const float* db   = (const float*)d_in[8];
    const float* g1   = (const float*)d_in[9];
    const float* b1   = (const float*)d_in[10];
    const float* w1   = (const float*)d_in[11];
    const float* w2   = (const float*)d_in[12];
    const float* g2   = (const float*)d_in[13];
    const float* b2   = (const float*)d_in[14];
    float* out = (float*)d_out;

    char* ws = (char*)d_ws;
    float* sintab = (float*)ws;                   // 255*64
    float* costab = sintab + 16384;
    float* rvbuf  = costab + 16384;               // 510
    unsigned short* Wt1 = (unsigned short*)(ws + 262144);
    unsigned short* Wt2 = (unsigned short*)(ws + 262144 + 294912);
    float* A  = (float*)(ws + (1u << 20));        // h_v, later c1 (bf16)
    float* Bb = A + 16646400;                     // v_v
    float* C  = Bb + 16646400;                    // QKV chunk, later v (LN1 output)
    float* Qc = C;
    float* Kc = C + 2774400;
    float* Vc = C + 5548800;
    unsigned short* c1b = (unsigned short*)A;

    k_tables<<<1, 256, 0, stream>>>(mask, sintab, costab, rvbuf);
    k_wconv<<<1152, 256, 0, stream>>>(w1, w2, Wt1, Wt2);
    for (int ch = 0; ch < NCH; ch++) {
        int r0 = ch * CH;
        k_qkv<0><<<339, 256, 0, stream>>>(x, pe, hW, hb, sintab, costab, Qc, Kc, Vc, r0);
        k_attn<<<dim3(8, CH), 256, 0, stream>>>(Qc, Kc, Vc, mask, A, r0);
        k_qkv<1><<<339, 256, 0, stream>>>(x, pe, vW, vbias, sintab, costab, Qc, Kc, Vc, r0);
        k_attn<<<dim3(8, CH), 256, 0, stream>>>(Qc, Kc, Vc, mask, Bb, r0);
    }
    k_dense_ln1<<<8129, 128, 0, stream>>>(A, Bb, dw, db, x, pe, rvbuf, g1, b1, C);
    k_convm<1><<<dim3(2, RR), 256, 0, stream>>>(C, nullptr, mask, Wt1, nullptr, nullptr, nullptr, c1b, nullptr);
    k_convm<2><<<dim3(2, RR), 256, 0, stream>>>(nullptr, c1b, mask, Wt2, C, g2, b2, nullptr, out);
}

// Round 3
// 765.695 us; speedup vs baseline: 11.9668x; 5.4112x over previous
//
#include <hip/hip_runtime.h>
#include <hip/hip_bf16.h>
#include <math.h>

constexpr int BSZ = 2;
constexpr int LL  = 255;
constexpr int WW  = 255;
constexpr int DD  = 128;
constexpr int RR  = BSZ * LL;     // 510 rows
constexpr int GG  = RR * WW;      // 130050 positions

typedef __attribute__((ext_vector_type(8))) short bf16x8;
typedef __attribute__((ext_vector_type(4))) float f32x4;
typedef unsigned short ushort_t;

__device__ __forceinline__ float clip1k(float v){ return fminf(fmaxf(v, -1000.f), 1000.f); }
__device__ __forceinline__ float clipT(float v){ return fminf(fmaxf(v, -10000.f), 10000.f); }
__device__ __forceinline__ unsigned short f2bf(float f){
    unsigned int u = __float_as_uint(f);
    unsigned int r = u + 0x7fffu + ((u >> 16) & 1u);
    return (unsigned short)(r >> 16);
}

// ---------------- tables ------------------------------------------------------------------
__global__ __launch_bounds__(256) void k_tables(const int* __restrict__ mask,
                                                float* __restrict__ sintab,
                                                float* __restrict__ costab,
                                                float* __restrict__ rv)
{
    int tid = threadIdx.x;
    for (int idx = tid; idx < WW * 64; idx += 256) {
        int p = idx >> 6, t = idx & 63;
        double freq = exp((double)t * (-9.210340371976184 / 64.0));
        double a = (double)p * freq;
        sintab[idx] = (float)sin(a);
        costab[idx] = (float)cos(a);
    }
    for (int r = tid; r < RR; r += 256) {
        const int* mr = mask + r * WW;
        int s = 0;
        for (int j = 0; j < WW; j++) s += mr[j];
        rv[r] = (s != WW) ? 1.f : 0.f;
    }
}

// ---------------- conv weight transpose to bf16 [o][ky*384+kx*128+c] ----------------------
__global__ __launch_bounds__(256) void k_wconv(const float* __restrict__ w1,
                                               const float* __restrict__ w2,
                                               ushort_t* __restrict__ Wt1,
                                               ushort_t* __restrict__ Wt2)
{
    int idx = blockIdx.x * 256 + threadIdx.x;
    if (idx >= 2 * 147456) return;
    int buf = idx / 147456, rem = idx % 147456;
    int o = rem / 1152, k = rem % 1152;
    int ky = k / 384, kx = (k % 384) / 128, c = k % 128;
    const float* w = buf ? w2 : w1;
    float v = w[((o * 128 + c) * 3 + ky) * 3 + kx];
    (buf ? Wt2 : Wt1)[rem] = f2bf(v);
}

// ---------------- misc weight bf16 converts ------------------------------------------------
__global__ __launch_bounds__(256) void k_wmisc(const float* __restrict__ hW,
                                               const float* __restrict__ vW,
                                               const float* __restrict__ dw,
                                               ushort_t* __restrict__ hWb,
                                               ushort_t* __restrict__ vWb,
                                               ushort_t* __restrict__ dwb)
{
    int idx = blockIdx.x * 256 + threadIdx.x;
    if (idx < 49152) { hWb[idx] = f2bf(hW[idx]); vWb[idx] = f2bf(vW[idx]); }
    if (idx < 32768) dwb[idx] = f2bf(dw[idx]);
}

// ---------------- MFMA QKV projection (+clip, +rotary, V transposed) -----------------------
template <int BRANCH>
__global__ __launch_bounds__(256, 2) void k_qkvm(const float* __restrict__ x,
                                                 const float* __restrict__ pe,
                                                 const ushort_t* __restrict__ Wb,
                                                 const float* __restrict__ bias,
                                                 const float* __restrict__ sintab,
                                                 const float* __restrict__ costab,
                                                 ushort_t* __restrict__ Qb,
                                                 ushort_t* __restrict__ Kb,
                                                 ushort_t* __restrict__ Vt)
{
    __shared__ ushort_t xs[128][136];
    const int tid = threadIdx.x;
    const int l = tid & 63, w = tid >> 6;
    const int l15 = l & 15, l4g = l >> 4;
    const int wr = w & 1, wc = w >> 1;
    const int tile0 = blockIdx.x * 128;

    // stage X' tile (clip + pos-embed, branch gather), bf16
    for (int it = 0; it < 8; it++) {
        int idx = it * 256 + tid;
        int p = idx >> 4, c8 = idx & 15;
        int gpos = tile0 + p;
        uint4 pk = make_uint4(0u, 0u, 0u, 0u);
        if (gpos < GG) {
            int j = gpos % 255;
            const float* src;
            int pidx;
            if (BRANCH == 0) {
                src = x + (size_t)gpos * DD + c8 * 8;
                pidx = (j < 127) ? 0 : 1;
            } else {
                int b = gpos / (LL * WW);
                int rem = gpos - b * (LL * WW);
                int i = rem / WW;
                int ri = (i + j + 128) % 255;
                int cj = 254 - j;
                src = x + (size_t)((b * LL + ri) * WW + cj) * DD + c8 * 8;
                pidx = (j <= 127) ? 1 : 0;
            }
            float4 a0 = *(const float4*)src;
            float4 a1 = *(const float4*)(src + 4);
            float4 p0 = *(const float4*)(pe + pidx * DD + c8 * 8);
            float4 p1 = *(const float4*)(pe + pidx * DD + c8 * 8 + 4);
            float e0 = clip1k(a0.x) + p0.x, e1 = clip1k(a0.y) + p0.y;
            float e2 = clip1k(a0.z) + p0.z, e3 = clip1k(a0.w) + p0.w;
            float e4 = clip1k(a1.x) + p1.x, e5 = clip1k(a1.y) + p1.y;
            float e6 = clip1k(a1.z) + p1.z, e7 = clip1k(a1.w) + p1.w;
            pk.x = f2bf(e0) | ((unsigned)f2bf(e1) << 16);
            pk.y = f2bf(e2) | ((unsigned)f2bf(e3) << 16);
            pk.z = f2bf(e4) | ((unsigned)f2bf(e5) << 16);
            pk.w = f2bf(e6) | ((unsigned)f2bf(e7) << 16);
        }
        *(uint4*)(&xs[p][c8 * 8]) = pk;
    }
    __syncthreads();

    for (int part = 0; part < 3; part++) {
        f32x4 acc[4][4];
        const f32x4 z4 = {0.f, 0.f, 0.f, 0.f};
        #pragma unroll
        for (int mt = 0; mt < 4; mt++)
            #pragma unroll
            for (int nt = 0; nt < 4; nt++) acc[mt][nt] = z4;

        #pragma unroll
        for (int kk = 0; kk < 4; kk++) {
            bf16x8 af[4], bf[4];
            #pragma unroll
            for (int mt = 0; mt < 4; mt++)
                af[mt] = *(const bf16x8*)(Wb + (size_t)(part * 128 + wr * 64 + mt * 16 + l15) * 128 + kk * 32 + l4g * 8);
            #pragma unroll
            for (int nt = 0; nt < 4; nt++)
                bf[nt] = *(const bf16x8*)(&xs[wc * 64 + nt * 16 + l15][kk * 32 + l4g * 8]);
            #pragma unroll
            for (int mt = 0; mt < 4; mt++)
                #pragma unroll
                for (int nt = 0; nt < 4; nt++)
                    acc[mt][nt] = __builtin_amdgcn_mfma_f32_16x16x32_bf16(af[mt], bf[nt], acc[mt][nt], 0, 0, 0);
        }

        // epilogue: bias + clip + rotary(Q,K) / transposed store (V)
        #pragma unroll
        for (int mt = 0; mt < 4; mt++) {
            int obase = wr * 64 + mt * 16 + l4g * 4;
            float4 bv = *(const float4*)(bias + part * 128 + obase);
            #pragma unroll
            for (int nt = 0; nt < 4; nt++) {
                int pl = wc * 64 + nt * 16 + l15;
                int gpos = tile0 + pl;
                if (gpos >= GG) continue;
                int rg = gpos / 255;
                int j = gpos - rg * 255;
                float v0 = clipT(acc[mt][nt][0] + bv.x);
                float v1 = clipT(acc[mt][nt][1] + bv.y);
                float v2 = clipT(acc[mt][nt][2] + bv.z);
                float v3 = clipT(acc[mt][nt][3] + bv.w);
                if (part < 2) {
                    int t0 = obase >> 1;
                    float cs0 = costab[j * 64 + t0],     sn0 = sintab[j * 64 + t0];
                    float cs1 = costab[j * 64 + t0 + 1], sn1 = sintab[j * 64 + t0 + 1];
                    float r0 = v0 * cs0 - v1 * sn0;
                    float r1 = v1 * cs0 + v0 * sn0;
                    float r2 = v2 * cs1 - v3 * sn1;
                    float r3 = v3 * cs1 + v2 * sn1;
                    uint2 pk;
                    pk.x = f2bf(r0) | ((unsigned)f2bf(r1) << 16);
                    pk.y = f2bf(r2) | ((unsigned)f2bf(r3) << 16);
                    ushort_t* dst = (part == 0) ? Qb : Kb;
                    *(uint2*)(dst + (size_t)gpos * 128 + obase) = pk;
                } else {
                    Vt[((size_t)(obase + 0) * 510 + rg) * 256 + j] = f2bf(v0);
                    Vt[((size_t)(obase + 1) * 510 + rg) * 256 + j] = f2bf(v1);
                    Vt[((size_t)(obase + 2) * 510 + rg) * 256 + j] = f2bf(v2);
                    Vt[((size_t)(obase + 3) * 510 + rg) * 256 + j] = f2bf(v3);
                }
            }
        }
    }
}

// ---------------- MFMA attention: one (row, 64q-tile) per block ----------------------------
__global__ __launch_bounds__(256, 2) void k_attn2(const ushort_t* __restrict__ Qb,
                                                  const ushort_t* __restrict__ Kb,
                                                  const ushort_t* __restrict__ Vt,
                                                  const int* __restrict__ mask,
                                                  ushort_t* __restrict__ outO)
{
    __shared__ char sSc[64 * 258 * 4];           // scores f32 [64][258], later pb bf16 [64][264]
    float* scores = (float*)sSc;
    ushort_t* pb = (ushort_t*)sSc;

    const int tid = threadIdx.x;
    const int l = tid & 63, w = tid >> 6;
    const int l15 = l & 15, l4g = l >> 4;
    const int qt = blockIdx.x, rg = blockIdx.y;
    const int q0 = qt * 64;
    const size_t rowbase = (size_t)rg * 255;
    const float iscale = 0.0883883476483184f;    // 1/sqrt(128)

    // ---- QK^T ----
    bf16x8 qf[4][4];
    const bf16x8 zf = {0, 0, 0, 0, 0, 0, 0, 0};
    #pragma unroll
    for (int mt = 0; mt < 4; mt++) {
        int q = q0 + mt * 16 + l15;
        #pragma unroll
        for (int kk = 0; kk < 4; kk++) {
            qf[mt][kk] = (q < 255) ? *(const bf16x8*)(Qb + (rowbase + q) * 128 + kk * 32 + l4g * 8) : zf;
        }
    }
    f32x4 acc[4][4];
    const f32x4 z4 = {0.f, 0.f, 0.f, 0.f};
    #pragma unroll
    for (int mt = 0; mt < 4; mt++)
        #pragma unroll
        for (int nt = 0; nt < 4; nt++) acc[mt][nt] = z4;

    #pragma unroll
    for (int kk = 0; kk < 4; kk++) {
        bf16x8 bf[4];
        #pragma unroll
        for (int nt = 0; nt < 4; nt++) {
            int kpos = w * 64 + nt * 16 + l15;
            bf[nt] = (kpos < 255) ? *(const bf16x8*)(Kb + (rowbase + kpos) * 128 + kk * 32 + l4g * 8) : zf;
        }
        #pragma unroll
        for (int mt = 0; mt < 4; mt++)
            #pragma unroll
            for (int nt = 0; nt < 4; nt++)
                acc[mt][nt] = __builtin_amdgcn_mfma_f32_16x16x32_bf16(qf[mt][kk], bf[nt], acc[mt][nt], 0, 0, 0);
    }

    // scores (with additive mask); col>=255 -> -1e38
    #pragma unroll
    for (int nt = 0; nt < 4; nt++) {
        int j = w * 64 + nt * 16 + l15;
        float madd = 0.f;
        bool jv = (j < 255);
        if (jv) madd = (mask[rowbase + j] > 0) ? -10000.f : 0.f;
        #pragma unroll
        for (int mt = 0; mt < 4; mt++) {
            #pragma unroll
            for (int r = 0; r < 4; r++) {
                int q = mt * 16 + l4g * 4 + r;
                float s = jv ? (clipT(acc[mt][nt][r] * iscale) + madd) : -1e38f;
                scores[q * 258 + j] = s;
            }
        }
    }
    __syncthreads();

    // ---- softmax: 4 lanes per q-row ----
    {
        int q = tid >> 2, l4 = tid & 3;
        float2 sv[32];
        float m = -3.0e38f;
        #pragma unroll
        for (int i = 0; i < 32; i++) {
            float2 v = *(const float2*)(&scores[q * 258 + 2 * l4 + 8 * i]);
            sv[i] = v;
            m = fmaxf(m, fmaxf(v.x, v.y));
        }
        m = fmaxf(m, __shfl_xor(m, 1));
        m = fmaxf(m, __shfl_xor(m, 2));
        float ssum = 0.f;
        #pragma unroll
        for (int i = 0; i < 32; i++) {
            float ex = __expf(sv[i].x - m);
            float ey = __expf(sv[i].y - m);
            ssum += ex + ey;
            // post-softmax zeroing: masked (additive -10000 => s < -5000 for real data) and pad
            sv[i].x = (sv[i].x > -5000.f) ? ex : 0.f;
            sv[i].y = (sv[i].y > -5000.f) ? ey : 0.f;
        }
        ssum += __shfl_xor(ssum, 1);
        ssum += __shfl_xor(ssum, 2);
        float inv = 1.f / ssum;
        __syncthreads();   // all score reads complete
        #pragma unroll
        for (int i = 0; i < 32; i++) {
            unsigned pk = f2bf(sv[i].x * inv) | ((unsigned)f2bf(sv[i].y * inv) << 16);
            *(unsigned*)(&pb[q * 264 + 2 * l4 + 8 * i]) = pk;
        }
    }
    __syncthreads();

    // ---- AV ----
    f32x4 av[4][2];
    #pragma unroll
    for (int mt = 0; mt < 4; mt++) { av[mt][0] = z4; av[mt][1] = z4; }
    #pragma unroll
    for (int kk = 0; kk < 8; kk++) {
        bf16x8 pa[4], vf[2];
        #pragma unroll
        for (int mt = 0; mt < 4; mt++)
            pa[mt] = *(const bf16x8*)(&pb[(mt * 16 + l15) * 264 + kk * 32 + l4g * 8]);
        #pragma unroll
        for (int nt = 0; nt < 2; nt++) {
            int d = w * 32 + nt * 16 + l15;
            vf[nt] = *(const bf16x8*)(Vt + ((size_t)d * 510 + rg) * 256 + kk * 32 + l4g * 8);
        }
        #pragma unroll
        for (int mt = 0; mt < 4; mt++)
            #pragma unroll
            for (int nt = 0; nt < 2; nt++)
                av[mt][nt] = __builtin_amdgcn_mfma_f32_16x16x32_bf16(pa[mt], vf[nt], av[mt][nt], 0, 0, 0);
    }
    // store
    #pragma unroll
    for (int mt = 0; mt < 4; mt++) {
        #pragma unroll
        for (int r = 0; r < 4; r++) {
            int q = q0 + mt * 16 + l4g * 4 + r;
            if (q < 255) {
                #pragma unroll
                for (int nt = 0; nt < 2; nt++) {
                    int d = w * 32 + nt * 16 + l15;
                    outO[(rowbase + q) * 128 + d] = f2bf(av[mt][nt][r]);
                }
            }
        }
    }
}

// ---------------- MFMA dense (concat 256 -> 128) + rv + residual + LN1 ---------------------
__global__ __launch_bounds__(256, 2) void k_dense2(const ushort_t* __restrict__ hv,
                                                   const ushort_t* __restrict__ vv,
                                                   const ushort_t* __restrict__ dwb,
                                                   const float* __restrict__ db,
                                                   const float* __restrict__ x,
                                                   const float* __restrict__ pe,
                                                   const float* __restrict__ rv,
                                                   const float* __restrict__ g1,
                                                   const float* __restrict__ b1,
                                                   float* __restrict__ C,
                                                   ushort_t* __restrict__ Cb)
{
    __shared__ float redS[128][2], redQ[128][2];
    const int tid = threadIdx.x;
    const int l = tid & 63, w = tid >> 6;
    const int l15 = l & 15, l4g = l >> 4;
    const int wr = w & 1, wc = w >> 1;
    const int tile0 = blockIdx.x * 128;

    f32x4 acc[4][4];
    const f32x4 z4 = {0.f, 0.f, 0.f, 0.f};
    #pragma unroll
    for (int mt = 0; mt < 4; mt++)
        #pragma unroll
        for (int nt = 0; nt < 4; nt++) acc[mt][nt] = z4;

    #pragma unroll
    for (int kk = 0; kk < 8; kk++) {
        bf16x8 af[4], bf[4];
        #pragma unroll
        for (int mt = 0; mt < 4; mt++) {
            int gpos = tile0 + wr * 64 + mt * 16 + l15;
            if (gpos >= GG) gpos = GG - 1;
            const ushort_t* srcp = (kk < 4) ? (hv + (size_t)gpos * 128 + kk * 32 + l4g * 8)
                                            : (vv + (size_t)gpos * 128 + (kk - 4) * 32 + l4g * 8);
            af[mt] = *(const bf16x8*)srcp;
        }
        #pragma unroll
        for (int nt = 0; nt < 4; nt++) {
            int o = wc * 64 + nt * 16 + l15;
            bf[nt] = *(const bf16x8*)(dwb + (size_t)o * 256 + kk * 32 + l4g * 8);
        }
        #pragma unroll
        for (int mt = 0; mt < 4; mt++)
            #pragma unroll
            for (int nt = 0; nt < 4; nt++)
                acc[mt][nt] = __builtin_amdgcn_mfma_f32_16x16x32_bf16(af[mt], bf[nt], acc[mt][nt], 0, 0, 0);
    }

    // epilogue: val = (acc + db)*rv + resid; LN over 128 channels (2 waves share rows)
    #pragma unroll
    for (int mt = 0; mt < 4; mt++) {
        #pragma unroll
        for (int r = 0; r < 4; r++) {
            int row = wr * 64 + mt * 16 + l4g * 4 + r;
            int gpos = tile0 + row;
            bool valid = (gpos < GG);
            int rg = valid ? gpos / 255 : 0;
            int j = gpos - rg * 255;
            float rvv = valid ? rv[rg] : 0.f;
            int pidx = (j < 127) ? 0 : 1;
            float s1 = 0.f, s2 = 0.f;
            #pragma unroll
            for (int nt = 0; nt < 4; nt++) {
                int o = wc * 64 + nt * 16 + l15;
                float resid = 0.f;
                if (valid) resid = clip1k(x[(size_t)gpos * 128 + o]) + pe[pidx * 128 + o];
                float v = (acc[mt][nt][r] + db[o]) * rvv + resid;
                acc[mt][nt][r] = v;
                s1 += v; s2 += v * v;
            }
            s1 += __shfl_xor(s1, 1); s2 += __shfl_xor(s2, 1);
            s1 += __shfl_xor(s1, 2); s2 += __shfl_xor(s2, 2);
            s1 += __shfl_xor(s1, 4); s2 += __shfl_xor(s2, 4);
            s1 += __shfl_xor(s1, 8); s2 += __shfl_xor(s2, 8);
            if (l15 == 0) { redS[row][wc] = s1; redQ[row][wc] = s2; }
        }
    }
    __syncthreads();
    #pragma unroll
    for (int mt = 0; mt < 4; mt++) {
        #pragma unroll
        for (int r = 0; r < 4; r++) {
            int row = wr * 64 + mt * 16 + l4g * 4 + r;
            int gpos = tile0 + row;
            if (gpos >= GG) continue;
            float mu = (redS[row][0] + redS[row][1]) * 0.0078125f;
            float q  = (redQ[row][0] + redQ[row][1]) * 0.0078125f;
            float inv = rsqrtf(q - mu * mu + 1e-5f);
            #pragma unroll
            for (int nt = 0; nt < 4; nt++) {
                int o = wc * 64 + nt * 16 + l15;
                float y = (acc[mt][nt][r] - mu) * inv * g1[o] + b1[o];
                C[(size_t)gpos * 128 + o] = y;
                Cb[(size_t)gpos * 128 + o] = f2bf(y);
            }
        }
    }
}

// ---------------- MFMA masked 3x3 conv (bf16 in). EPI 0: gelu->bf16. EPI 1: +vb,LN2->f32 ---
template <int EPI>
__global__ __launch_bounds__(256, 2) void k_convm(const ushort_t* __restrict__ inB,
                                                  const int* __restrict__ mask,
                                                  const ushort_t* __restrict__ Wt,
                                                  const float* __restrict__ vb,
                                                  const float* __restrict__ g2,
                                                  const float* __restrict__ b2,
                                                  ushort_t* __restrict__ outB,
                                                  float* __restrict__ outF)
{
    __shared__ ushort_t s_a[132][136];
    __shared__ ushort_t s_b[2][128][40];
    __shared__ float redS[128][2], redQ[128][2];

    const int tid = threadIdx.x;
    const int l  = tid & 63, lrn = l & 15, lgp = l >> 4;
    const int w  = tid >> 6, wr = w & 1, wc = w >> 1;
    const int r  = blockIdx.y, b = r / LL, i = r % LL;
    const int j0 = blockIdx.x * 128;

    f32x4 acc[4][4];
    const f32x4 z4 = {0.f, 0.f, 0.f, 0.f};
    #pragma unroll
    for (int jt = 0; jt < 4; jt++)
        #pragma unroll
        for (int ot = 0; ot < 4; ot++) acc[jt][ot] = z4;

    for (int ky = 0; ky < 3; ky++) {
        const int ri = i + ky - 1;
        for (int t = tid; t < 132 * 16; t += 256) {
            int col = t >> 4, c8 = t & 15;
            int nj = j0 - 1 + col;
            int4 pk = make_int4(0, 0, 0, 0);
            if (ri >= 0 && ri < LL && nj >= 0 && nj < WW) {
                int mp = (b * LL + ri) * WW + nj;
                if (mask[mp] == 0) pk = *(const int4*)(inB + (size_t)mp * DD + c8 * 8);
            }
            *(int4*)(&s_a[col][c8 * 8]) = pk;
        }
        {
            const int kb = ky * 384;
            #pragma unroll
            for (int it = 0; it < 2; it++) {
                int idx = it * 256 + tid, o = idx >> 2, q = idx & 3;
                *(int4*)(&s_b[0][o][q * 8]) = *(const int4*)(Wt + (size_t)o * 1152 + kb + q * 8);
            }
        }
        __syncthreads();

        for (int s = 0; s < 12; s++) {
            if (s < 11) {
                const int kb = ky * 384 + (s + 1) * 32;
                const int bufn = (s + 1) & 1;
                #pragma unroll
                for (int it = 0; it < 2; it++) {
                    int idx = it * 256 + tid, o = idx >> 2, q = idx & 3;
                    *(int4*)(&s_b[bufn][o][q * 8]) = *(const int4*)(Wt + (size_t)o * 1152 + kb + q * 8);
                }
            }
            const int kx = s >> 2;
            const int c0 = (s & 3) * 32 + lgp * 8;
            const int buf = s & 1;
            bf16x8 af[4], bfr[4];
            #pragma unroll
            for (int jt = 0; jt < 4; jt++) {
                int col = wr * 64 + jt * 16 + lrn + kx;
                af[jt] = *(const bf16x8*)(&s_a[col][c0]);
            }
            #pragma unroll
            for (int ot = 0; ot < 4; ot++) {
                int o = wc * 64 + ot * 16 + lrn;
                bfr[ot] = *(const bf16x8*)(&s_b[buf][o][lgp * 8]);
            }
            #pragma unroll
            for (int jt = 0; jt < 4; jt++)
                #pragma unroll
                for (int ot = 0; ot < 4; ot++)
                    acc[jt][ot] = __builtin_amdgcn_mfma_f32_16x16x32_bf16(af[jt], bfr[ot], acc[jt][ot], 0, 0, 0);
            __syncthreads();
        }
    }

    if (EPI == 0) {
        #pragma unroll
        for (int jt = 0; jt < 4; jt++) {
            #pragma unroll
            for (int r4 = 0; r4 < 4; r4++) {
                int jl = wr * 64 + jt * 16 + lgp * 4 + r4;
                int j = j0 + jl;
                if (j >= WW) continue;
                size_t gp = (size_t)((b * LL + i) * WW + j) * DD;
                #pragma unroll
                for (int ot = 0; ot < 4; ot++) {
                    int o = wc * 64 + ot * 16 + lrn;
                    float a = acc[jt][ot][r4];
                    float y = 0.5f * a * (1.f + erff(a * 0.70710678118654752f));
                    outB[gp + o] = f2bf(y);
                }
            }
        }
    } else {
        float g2v[4], b2v[4];
        #pragma unroll
        for (int ot = 0; ot < 4; ot++) {
            int o = wc * 64 + ot * 16 + lrn;
            g2v[ot] = g2[o]; b2v[ot] = b2[o];
        }
        #pragma unroll
        for (int jt = 0; jt < 4; jt++) {
            #pragma unroll
            for (int r4 = 0; r4 < 4; r4++) {
                int jl = wr * 64 + jt * 16 + lgp * 4 + r4;
                int j = j0 + jl;
                float s1 = 0.f, s2 = 0.f;
                if (j < WW) {
                    size_t gp = (size_t)((b * LL + i) * WW + j) * DD;
                    #pragma unroll
                    for (int ot = 0; ot < 4; ot++) {
                        int o = wc * 64 + ot * 16 + lrn;
                        float v = acc[jt][ot][r4] + vb[gp + o];
                        acc[jt][ot][r4] = v;
                        s1 += v; s2 += v * v;
                    }
                }
                #pragma unroll
                for (int off = 1; off < 16; off <<= 1) {
                    s1 += __shfl_xor(s1, off);
                    s2 += __shfl_xor(s2, off);
                }
                if (lrn == 0) { redS[jl][wc] = s1; redQ[jl][wc] = s2; }
            }
        }
        __syncthreads();
        #pragma unroll
        for (int jt = 0; jt < 4; jt++) {
            #pragma unroll
            for (int r4 = 0; r4 < 4; r4++) {
                int jl = wr * 64 + jt * 16 + lgp * 4 + r4;
                int j = j0 + jl;
                if (j >= WW) continue;
                float mu = (redS[jl][0] + redS[jl][1]) * 0.0078125f;
                float q  = (redQ[jl][0] + redQ[jl][1]) * 0.0078125f;
                float inv = rsqrtf(q - mu * mu + 1e-5f);
                size_t gp = (size_t)((b * LL + i) * WW + j) * DD;
                #pragma unroll
                for (int ot = 0; ot < 4; ot++) {
                    int o = wc * 64 + ot * 16 + lrn;
                    outF[gp + o] = (acc[jt][ot][r4] - mu) * inv * g2v[ot] + b2v[ot];
                }
            }
        }
    }
}

extern "C" void kernel_launch(void* const* d_in, const int* in_sizes, int n_in,
                              void* d_out, int out_size, void* d_ws, size_t ws_size,
                              hipStream_t stream)
{
    (void)in_sizes; (void)n_in; (void)out_size; (void)ws_size;
    const float* x    = (const float*)d_in[0];
    const int*   mask = (const int*)d_in[1];
    const float* pe   = (const float*)d_in[2];
    const float* hW   = (const float*)d_in[3];
    const float* hb   = (const float*)d_in[4];
    const float* vW   = (const float*)d_in[5];
    const float* vbias= (const float*)d_in[6];
    const float* dw   = (const float*)d_in[7];
    const float* db   = (const float*)d_in[8];
    const float* g1   = (const float*)d_in[9];
    const float* b1   = (const float*)d_in[10];
    const float* w1   = (const float*)d_in[11];
    const float* w2   = (const float*)d_in[12];
    const float* g2   = (const float*)d_in[13];
    const float* b2   = (const float*)d_in[14];
    float* out = (float*)d_out;

    char* ws = (char*)d_ws;
    float* sintab = (float*)(ws + 0);            // 65536 B
    float* costab = (float*)(ws + 65536);        // 65536 B
    float* rvbuf  = (float*)(ws + 131072);       // 2048 B
    ushort_t* hWb = (ushort_t*)(ws + 143360);    // 98304 B
    ushort_t* vWb = (ushort_t*)(ws + 241664);    // 98304 B
    ushort_t* dwb = (ushort_t*)(ws + 339968);    // 65536 B
    ushort_t* Wt1 = (ushort_t*)(ws + 405504);    // 294912 B
    ushort_t* Wt2 = (ushort_t*)(ws + 700416);    // 294912 B

    const size_t R0 = 2097152;
    ushort_t* Qb = (ushort_t*)(ws + R0);                      // 33,292,800 B
    ushort_t* Kb = (ushort_t*)(ws + R0 + 33292800);           // 33,292,800 B
    ushort_t* Vt = (ushort_t*)(ws + R0 + 66585600);           // 33,423,360 B (128*510*256)
    float*    C  = (float*)(ws + R0);                         // 66,585,600 B (overlaps Qb+Kb, dead)
    ushort_t* Cb = (ushort_t*)(ws + R0 + 66585600);           // 33,292,800 B (overlaps Vt, dead)
    ushort_t* hvb = (ushort_t*)(ws + 102760448);              // 33,292,800 B
    ushort_t* vvb = (ushort_t*)(ws + 136314880);              // 33,292,800 B
    ushort_t* c1b = vvb;                                      // reuse after dense

    k_tables<<<1, 256, 0, stream>>>(mask, sintab, costab, rvbuf);
    k_wconv<<<1152, 256, 0, stream>>>(w1, w2, Wt1, Wt2);
    k_wmisc<<<192, 256, 0, stream>>>(hW, vW, dw, hWb, vWb, dwb);

    k_qkvm<0><<<1017, 256, 0, stream>>>(x, pe, hWb, hb, sintab, costab, Qb, Kb, Vt);
    k_attn2<<<dim3(4, RR), 256, 0, stream>>>(Qb, Kb, Vt, mask, hvb);
    k_qkvm<1><<<1017, 256, 0, stream>>>(x, pe, vWb, vbias, sintab, costab, Qb, Kb, Vt);
    k_attn2<<<dim3(4, RR), 256, 0, stream>>>(Qb, Kb, Vt, mask, vvb);

    k_dense2<<<1017, 256, 0, stream>>>(hvb, vvb, dwb, db, x, pe, rvbuf, g1, b1, C, Cb);
    k_convm<0><<<dim3(2, RR), 256, 0, stream>>>(Cb, mask, Wt1, nullptr, nullptr, nullptr, c1b, nullptr);
    k_convm<1><<<dim3(2, RR), 256, 0, stream>>>(c1b, mask, Wt2, C, g2, b2, nullptr, out);
}

// Round 4
// 627.351 us; speedup vs baseline: 14.6058x; 1.2205x over previous
//
#include <hip/hip_runtime.h>
#include <hip/hip_bf16.h>
#include <math.h>

constexpr int BSZ = 2;
constexpr int LL  = 255;
constexpr int WW  = 255;
constexpr int DD  = 128;
constexpr int RR  = BSZ * LL;     // 510 rows
constexpr int GG  = RR * WW;      // 130050 positions

typedef __attribute__((ext_vector_type(8))) short bf16x8;
typedef __attribute__((ext_vector_type(4))) float f32x4;
typedef unsigned short ushort_t;

__device__ __forceinline__ float clip1k(float v){ return fminf(fmaxf(v, -1000.f), 1000.f); }
__device__ __forceinline__ float clipT(float v){ return fminf(fmaxf(v, -10000.f), 10000.f); }
__device__ __forceinline__ unsigned short f2bf(float f){
    unsigned int u = __float_as_uint(f);
    unsigned int r = u + 0x7fffu + ((u >> 16) & 1u);
    return (unsigned short)(r >> 16);
}

// ---------------- tables ------------------------------------------------------------------
__global__ __launch_bounds__(256) void k_tables(const int* __restrict__ mask,
                                                float* __restrict__ sintab,
                                                float* __restrict__ costab,
                                                float* __restrict__ rv)
{
    int tid = threadIdx.x;
    for (int idx = tid; idx < WW * 64; idx += 256) {
        int p = idx >> 6, t = idx & 63;
        double freq = exp((double)t * (-9.210340371976184 / 64.0));
        double a = (double)p * freq;
        sintab[idx] = (float)sin(a);
        costab[idx] = (float)cos(a);
    }
    for (int r = tid; r < RR; r += 256) {
        const int* mr = mask + r * WW;
        int s = 0;
        for (int j = 0; j < WW; j++) s += mr[j];
        rv[r] = (s != WW) ? 1.f : 0.f;
    }
}

// ---------------- conv weight transpose to bf16 [o][ky*384+kx*128+c] ----------------------
__global__ __launch_bounds__(256) void k_wconv(const float* __restrict__ w1,
                                               const float* __restrict__ w2,
                                               ushort_t* __restrict__ Wt1,
                                               ushort_t* __restrict__ Wt2)
{
    int idx = blockIdx.x * 256 + threadIdx.x;
    if (idx >= 2 * 147456) return;
    int buf = idx / 147456, rem = idx % 147456;
    int o = rem / 1152, k = rem % 1152;
    int ky = k / 384, kx = (k % 384) / 128, c = k % 128;
    const float* w = buf ? w2 : w1;
    float v = w[((o * 128 + c) * 3 + ky) * 3 + kx];
    (buf ? Wt2 : Wt1)[rem] = f2bf(v);
}

// ---------------- misc weight bf16 converts ------------------------------------------------
__global__ __launch_bounds__(256) void k_wmisc(const float* __restrict__ hW,
                                               const float* __restrict__ vW,
                                               const float* __restrict__ dw,
                                               ushort_t* __restrict__ hWb,
                                               ushort_t* __restrict__ vWb,
                                               ushort_t* __restrict__ dwb)
{
    int idx = blockIdx.x * 256 + threadIdx.x;
    if (idx < 49152) { hWb[idx] = f2bf(hW[idx]); vWb[idx] = f2bf(vW[idx]); }
    if (idx < 32768) dwb[idx] = f2bf(dw[idx]);
}

// ---------------- MFMA QKV projection (+clip, +rotary, V transposed) -----------------------
template <int BRANCH>
__global__ __launch_bounds__(256, 2) void k_qkvm(const float* __restrict__ x,
                                                 const float* __restrict__ pe,
                                                 const ushort_t* __restrict__ Wb,
                                                 const float* __restrict__ bias,
                                                 const float* __restrict__ sintab,
                                                 const float* __restrict__ costab,
                                                 ushort_t* __restrict__ Qb,
                                                 ushort_t* __restrict__ Kb,
                                                 ushort_t* __restrict__ Vt)
{
    __shared__ ushort_t xs[128][136];
    __shared__ ushort_t os[128][136];   // output staging (coalesced global stores)
    const int tid = threadIdx.x;
    const int l = tid & 63, w = tid >> 6;
    const int l15 = l & 15, l4g = l >> 4;
    const int wr = w & 1, wc = w >> 1;
    const int tile0 = blockIdx.x * 128;

    // stage X' tile (clip + pos-embed, branch gather), bf16
    for (int it = 0; it < 8; it++) {
        int idx = it * 256 + tid;
        int p = idx >> 4, c8 = idx & 15;
        int gpos = tile0 + p;
        uint4 pk = make_uint4(0u, 0u, 0u, 0u);
        if (gpos < GG) {
            int j = gpos % 255;
            const float* src;
            int pidx;
            if (BRANCH == 0) {
                src = x + (size_t)gpos * DD + c8 * 8;
                pidx = (j < 127) ? 0 : 1;
            } else {
                int b = gpos / (LL * WW);
                int rem = gpos - b * (LL * WW);
                int i = rem / WW;
                int ri = (i + j + 128) % 255;
                int cj = 254 - j;
                src = x + (size_t)((b * LL + ri) * WW + cj) * DD + c8 * 8;
                pidx = (j <= 127) ? 1 : 0;
            }
            float4 a0 = *(const float4*)src;
            float4 a1 = *(const float4*)(src + 4);
            float4 p0 = *(const float4*)(pe + pidx * DD + c8 * 8);
            float4 p1 = *(const float4*)(pe + pidx * DD + c8 * 8 + 4);
            float e0 = clip1k(a0.x) + p0.x, e1 = clip1k(a0.y) + p0.y;
            float e2 = clip1k(a0.z) + p0.z, e3 = clip1k(a0.w) + p0.w;
            float e4 = clip1k(a1.x) + p1.x, e5 = clip1k(a1.y) + p1.y;
            float e6 = clip1k(a1.z) + p1.z, e7 = clip1k(a1.w) + p1.w;
            pk.x = f2bf(e0) | ((unsigned)f2bf(e1) << 16);
            pk.y = f2bf(e2) | ((unsigned)f2bf(e3) << 16);
            pk.z = f2bf(e4) | ((unsigned)f2bf(e5) << 16);
            pk.w = f2bf(e6) | ((unsigned)f2bf(e7) << 16);
        }
        *(uint4*)(&xs[p][c8 * 8]) = pk;
    }
    __syncthreads();

    for (int part = 0; part < 3; part++) {
        f32x4 acc[4][4];
        const f32x4 z4 = {0.f, 0.f, 0.f, 0.f};
        #pragma unroll
        for (int mt = 0; mt < 4; mt++)
            #pragma unroll
            for (int nt = 0; nt < 4; nt++) acc[mt][nt] = z4;

        #pragma unroll
        for (int kk = 0; kk < 4; kk++) {
            bf16x8 af[4], bf[4];
            #pragma unroll
            for (int mt = 0; mt < 4; mt++)
                af[mt] = *(const bf16x8*)(Wb + (size_t)(part * 128 + wr * 64 + mt * 16 + l15) * 128 + kk * 32 + l4g * 8);
            #pragma unroll
            for (int nt = 0; nt < 4; nt++)
                bf[nt] = *(const bf16x8*)(&xs[wc * 64 + nt * 16 + l15][kk * 32 + l4g * 8]);
            #pragma unroll
            for (int mt = 0; mt < 4; mt++)
                #pragma unroll
                for (int nt = 0; nt < 4; nt++)
                    acc[mt][nt] = __builtin_amdgcn_mfma_f32_16x16x32_bf16(af[mt], bf[nt], acc[mt][nt], 0, 0, 0);
        }

        // epilogue: bias + clip + rotary(Q,K) / LDS transpose (V); all -> os staging
        #pragma unroll
        for (int mt = 0; mt < 4; mt++) {
            int obase = wr * 64 + mt * 16 + l4g * 4;
            float4 bv = *(const float4*)(bias + part * 128 + obase);
            #pragma unroll
            for (int nt = 0; nt < 4; nt++) {
                int pl = wc * 64 + nt * 16 + l15;
                int gpos = tile0 + pl;
                int j = (gpos < GG) ? (gpos % 255) : 0;
                float v0 = clipT(acc[mt][nt][0] + bv.x);
                float v1 = clipT(acc[mt][nt][1] + bv.y);
                float v2 = clipT(acc[mt][nt][2] + bv.z);
                float v3 = clipT(acc[mt][nt][3] + bv.w);
                if (part < 2) {
                    int t0 = obase >> 1;
                    float cs0 = costab[j * 64 + t0],     sn0 = sintab[j * 64 + t0];
                    float cs1 = costab[j * 64 + t0 + 1], sn1 = sintab[j * 64 + t0 + 1];
                    float r0 = v0 * cs0 - v1 * sn0;
                    float r1 = v1 * cs0 + v0 * sn0;
                    float r2 = v2 * cs1 - v3 * sn1;
                    float r3 = v3 * cs1 + v2 * sn1;
                    *(unsigned*)(&os[pl][obase])     = f2bf(r0) | ((unsigned)f2bf(r1) << 16);
                    *(unsigned*)(&os[pl][obase + 2]) = f2bf(r2) | ((unsigned)f2bf(r3) << 16);
                } else {
                    os[obase + 0][pl] = f2bf(v0);
                    os[obase + 1][pl] = f2bf(v1);
                    os[obase + 2][pl] = f2bf(v2);
                    os[obase + 3][pl] = f2bf(v3);
                }
            }
        }
        __syncthreads();

        if (part < 2) {
            ushort_t* dst = (part == 0) ? Qb : Kb;
            #pragma unroll
            for (int it = 0; it < 8; it++) {
                int idx = it * 256 + tid;
                int p = idx >> 4, c8 = idx & 15;
                int gpos = tile0 + p;
                if (gpos < GG) *(uint4*)(dst + (size_t)gpos * 128 + c8 * 8) = *(const uint4*)(&os[p][c8 * 8]);
            }
        } else {
            for (int it = 0; it < 64; it++) {
                int idx = it * 256 + tid;
                int d = idx >> 7, p = idx & 127;
                int gpos = tile0 + p;
                if (gpos < GG) {
                    int rg = gpos / 255, j = gpos - rg * 255;
                    Vt[((size_t)d * 510 + rg) * 256 + j] = os[d][p];
                }
            }
        }
        __syncthreads();
    }
}

// ---------------- MFMA attention: one (row, 64q-tile) per block ----------------------------
__global__ __launch_bounds__(256, 2) void k_attn2(const ushort_t* __restrict__ Qb,
                                                  const ushort_t* __restrict__ Kb,
                                                  const ushort_t* __restrict__ Vt,
                                                  const int* __restrict__ mask,
                                                  ushort_t* __restrict__ outO)
{
    __shared__ char sSc[64 * 258 * 4];           // scores f32 [64][258] / pb bf16 / O staging
    float* scores = (float*)sSc;
    ushort_t* pb = (ushort_t*)sSc;

    const int tid = threadIdx.x;
    const int l = tid & 63, w = tid >> 6;
    const int l15 = l & 15, l4g = l >> 4;
    const int qt = blockIdx.x, rg = blockIdx.y;
    const int q0 = qt * 64;
    const size_t rowbase = (size_t)rg * 255;
    const float iscale = 0.0883883476483184f;    // 1/sqrt(128)

    // ---- QK^T ----
    bf16x8 qf[4][4];
    const bf16x8 zf = {0, 0, 0, 0, 0, 0, 0, 0};
    #pragma unroll
    for (int mt = 0; mt < 4; mt++) {
        int q = q0 + mt * 16 + l15;
        #pragma unroll
        for (int kk = 0; kk < 4; kk++) {
            qf[mt][kk] = (q < 255) ? *(const bf16x8*)(Qb + (rowbase + q) * 128 + kk * 32 + l4g * 8) : zf;
        }
    }
    f32x4 acc[4][4];
    const f32x4 z4 = {0.f, 0.f, 0.f, 0.f};
    #pragma unroll
    for (int mt = 0; mt < 4; mt++)
        #pragma unroll
        for (int nt = 0; nt < 4; nt++) acc[mt][nt] = z4;

    #pragma unroll
    for (int kk = 0; kk < 4; kk++) {
        bf16x8 bf[4];
        #pragma unroll
        for (int nt = 0; nt < 4; nt++) {
            int kpos = w * 64 + nt * 16 + l15;
            bf[nt] = (kpos < 255) ? *(const bf16x8*)(Kb + (rowbase + kpos) * 128 + kk * 32 + l4g * 8) : zf;
        }
        #pragma unroll
        for (int mt = 0; mt < 4; mt++)
            #pragma unroll
            for (int nt = 0; nt < 4; nt++)
                acc[mt][nt] = __builtin_amdgcn_mfma_f32_16x16x32_bf16(qf[mt][kk], bf[nt], acc[mt][nt], 0, 0, 0);
    }

    // scores (with additive mask); col>=255 -> -1e38
    #pragma unroll
    for (int nt = 0; nt < 4; nt++) {
        int j = w * 64 + nt * 16 + l15;
        float madd = 0.f;
        bool jv = (j < 255);
        if (jv) madd = (mask[rowbase + j] > 0) ? -10000.f : 0.f;
        #pragma unroll
        for (int mt = 0; mt < 4; mt++) {
            #pragma unroll
            for (int r = 0; r < 4; r++) {
                int q = mt * 16 + l4g * 4 + r;
                float s = jv ? (clipT(acc[mt][nt][r] * iscale) + madd) : -1e38f;
                scores[q * 258 + j] = s;
            }
        }
    }
    __syncthreads();

    // ---- softmax: 4 lanes per q-row ----
    {
        int q = tid >> 2, l4 = tid & 3;
        float2 sv[32];
        float m = -3.0e38f;
        #pragma unroll
        for (int i = 0; i < 32; i++) {
            float2 v = *(const float2*)(&scores[q * 258 + 2 * l4 + 8 * i]);
            sv[i] = v;
            m = fmaxf(m, fmaxf(v.x, v.y));
        }
        m = fmaxf(m, __shfl_xor(m, 1));
        m = fmaxf(m, __shfl_xor(m, 2));
        float ssum = 0.f;
        #pragma unroll
        for (int i = 0; i < 32; i++) {
            float ex = __expf(sv[i].x - m);
            float ey = __expf(sv[i].y - m);
            ssum += ex + ey;
            sv[i].x = (sv[i].x > -5000.f) ? ex : 0.f;
            sv[i].y = (sv[i].y > -5000.f) ? ey : 0.f;
        }
        ssum += __shfl_xor(ssum, 1);
        ssum += __shfl_xor(ssum, 2);
        float inv = 1.f / ssum;
        __syncthreads();   // all score reads complete
        #pragma unroll
        for (int i = 0; i < 32; i++) {
            unsigned pk = f2bf(sv[i].x * inv) | ((unsigned)f2bf(sv[i].y * inv) << 16);
            *(unsigned*)(&pb[q * 264 + 2 * l4 + 8 * i]) = pk;
        }
    }
    __syncthreads();

    // ---- AV ----
    f32x4 av[4][2];
    #pragma unroll
    for (int mt = 0; mt < 4; mt++) { av[mt][0] = z4; av[mt][1] = z4; }
    #pragma unroll
    for (int kk = 0; kk < 8; kk++) {
        bf16x8 pa[4], vf[2];
        #pragma unroll
        for (int mt = 0; mt < 4; mt++)
            pa[mt] = *(const bf16x8*)(&pb[(mt * 16 + l15) * 264 + kk * 32 + l4g * 8]);
        #pragma unroll
        for (int nt = 0; nt < 2; nt++) {
            int d = w * 32 + nt * 16 + l15;
            vf[nt] = *(const bf16x8*)(Vt + ((size_t)d * 510 + rg) * 256 + kk * 32 + l4g * 8);
        }
        #pragma unroll
        for (int mt = 0; mt < 4; mt++)
            #pragma unroll
            for (int nt = 0; nt < 2; nt++)
                av[mt][nt] = __builtin_amdgcn_mfma_f32_16x16x32_bf16(pa[mt], vf[nt], av[mt][nt], 0, 0, 0);
    }

    // ---- stage O in LDS (overwrites pb), then coalesced store ----
    __syncthreads();
    ushort_t* osA = (ushort_t*)sSc;   // [64][136]
    #pragma unroll
    for (int mt = 0; mt < 4; mt++) {
        #pragma unroll
        for (int r = 0; r < 4; r++) {
            int ql = mt * 16 + l4g * 4 + r;
            #pragma unroll
            for (int nt = 0; nt < 2; nt++) {
                int d = w * 32 + nt * 16 + l15;
                osA[ql * 136 + d] = f2bf(av[mt][nt][r]);
            }
        }
    }
    __syncthreads();
    #pragma unroll
    for (int it = 0; it < 4; it++) {
        int idx = it * 256 + tid;
        int p = idx >> 4, c8 = idx & 15;
        int q = q0 + p;
        if (q < 255) *(uint4*)(outO + (rowbase + q) * 128 + c8 * 8) = *(const uint4*)(&osA[p * 136 + c8 * 8]);
    }
}

// ---------------- MFMA dense (concat 256 -> 128) + rv + residual + LN1 ---------------------
__global__ __launch_bounds__(256, 2) void k_dense2(const ushort_t* __restrict__ hv,
                                                   const ushort_t* __restrict__ vv,
                                                   const ushort_t* __restrict__ dwb,
                                                   const float* __restrict__ db,
                                                   const float* __restrict__ x,
                                                   const float* __restrict__ pe,
                                                   const float* __restrict__ rv,
                                                   const float* __restrict__ g1,
                                                   const float* __restrict__ b1,
                                                   float* __restrict__ C,
                                                   ushort_t* __restrict__ Cb)
{
    __shared__ float redS[128][2], redQ[128][2];
    __shared__ ushort_t os[128][136];
    const int tid = threadIdx.x;
    const int l = tid & 63, w = tid >> 6;
    const int l15 = l & 15, l4g = l >> 4;
    const int wr = w & 1, wc = w >> 1;
    const int tile0 = blockIdx.x * 128;

    f32x4 acc[4][4];
    const f32x4 z4 = {0.f, 0.f, 0.f, 0.f};
    #pragma unroll
    for (int mt = 0; mt < 4; mt++)
        #pragma unroll
        for (int nt = 0; nt < 4; nt++) acc[mt][nt] = z4;

    #pragma unroll
    for (int kk = 0; kk < 8; kk++) {
        bf16x8 af[4], bf[4];
        #pragma unroll
        for (int mt = 0; mt < 4; mt++) {
            int gpos = tile0 + wr * 64 + mt * 16 + l15;
            if (gpos >= GG) gpos = GG - 1;
            const ushort_t* srcp = (kk < 4) ? (hv + (size_t)gpos * 128 + kk * 32 + l4g * 8)
                                            : (vv + (size_t)gpos * 128 + (kk - 4) * 32 + l4g * 8);
            af[mt] = *(const bf16x8*)srcp;
        }
        #pragma unroll
        for (int nt = 0; nt < 4; nt++) {
            int o = wc * 64 + nt * 16 + l15;
            bf[nt] = *(const bf16x8*)(dwb + (size_t)o * 256 + kk * 32 + l4g * 8);
        }
        #pragma unroll
        for (int mt = 0; mt < 4; mt++)
            #pragma unroll
            for (int nt = 0; nt < 4; nt++)
                acc[mt][nt] = __builtin_amdgcn_mfma_f32_16x16x32_bf16(af[mt], bf[nt], acc[mt][nt], 0, 0, 0);
    }

    // epilogue: val = (acc + db)*rv + resid; LN over 128 channels (2 waves share rows)
    #pragma unroll
    for (int mt = 0; mt < 4; mt++) {
        #pragma unroll
        for (int r = 0; r < 4; r++) {
            int row = wr * 64 + mt * 16 + l4g * 4 + r;
            int gpos = tile0 + row;
            bool valid = (gpos < GG);
            int rg = valid ? gpos / 255 : 0;
            int j = gpos - rg * 255;
            float rvv = valid ? rv[rg] : 0.f;
            int pidx = (j < 127) ? 0 : 1;
            float s1 = 0.f, s2 = 0.f;
            #pragma unroll
            for (int nt = 0; nt < 4; nt++) {
                int o = wc * 64 + nt * 16 + l15;
                float resid = 0.f;
                if (valid) resid = clip1k(x[(size_t)gpos * 128 + o]) + pe[pidx * 128 + o];
                float v = (acc[mt][nt][r] + db[o]) * rvv + resid;
                acc[mt][nt][r] = v;
                s1 += v; s2 += v * v;
            }
            s1 += __shfl_xor(s1, 1); s2 += __shfl_xor(s2, 1);
            s1 += __shfl_xor(s1, 2); s2 += __shfl_xor(s2, 2);
            s1 += __shfl_xor(s1, 4); s2 += __shfl_xor(s2, 4);
            s1 += __shfl_xor(s1, 8); s2 += __shfl_xor(s2, 8);
            if (l15 == 0) { redS[row][wc] = s1; redQ[row][wc] = s2; }
        }
    }
    __syncthreads();
    #pragma unroll
    for (int mt = 0; mt < 4; mt++) {
        #pragma unroll
        for (int r = 0; r < 4; r++) {
            int row = wr * 64 + mt * 16 + l4g * 4 + r;
            int gpos = tile0 + row;
            if (gpos >= GG) continue;
            float mu = (redS[row][0] + redS[row][1]) * 0.0078125f;
            float q  = (redQ[row][0] + redQ[row][1]) * 0.0078125f;
            float inv = rsqrtf(q - mu * mu + 1e-5f);
            #pragma unroll
            for (int nt = 0; nt < 4; nt++) {
                int o = wc * 64 + nt * 16 + l15;
                float y = (acc[mt][nt][r] - mu) * inv * g1[o] + b1[o];
                C[(size_t)gpos * 128 + o] = y;
                os[row][o] = f2bf(y);
            }
        }
    }
    __syncthreads();
    #pragma unroll
    for (int it = 0; it < 8; it++) {
        int idx = it * 256 + tid;
        int p = idx >> 4, c8 = idx & 15;
        int gpos = tile0 + p;
        if (gpos < GG) *(uint4*)(Cb + (size_t)gpos * 128 + c8 * 8) = *(const uint4*)(&os[p][c8 * 8]);
    }
}

// ---------------- MFMA masked 3x3 conv (bf16 in). EPI 0: gelu->bf16. EPI 1: +vb,LN2->f32 ---
template <int EPI>
__global__ __launch_bounds__(256, 2) void k_convm(const ushort_t* __restrict__ inB,
                                                  const int* __restrict__ mask,
                                                  const ushort_t* __restrict__ Wt,
                                                  const float* __restrict__ vb,
                                                  const float* __restrict__ g2,
                                                  const float* __restrict__ b2,
                                                  ushort_t* __restrict__ outB,
                                                  float* __restrict__ outF)
{
    __shared__ ushort_t s_a[132][136];
    __shared__ ushort_t s_b[2][128][40];
    __shared__ float redS[128][2], redQ[128][2];

    const int tid = threadIdx.x;
    const int l  = tid & 63, lrn = l & 15, lgp = l >> 4;
    const int w  = tid >> 6, wr = w & 1, wc = w >> 1;
    const int r  = blockIdx.y, b = r / LL, i = r % LL;
    const int j0 = blockIdx.x * 128;

    f32x4 acc[4][4];
    const f32x4 z4 = {0.f, 0.f, 0.f, 0.f};
    #pragma unroll
    for (int jt = 0; jt < 4; jt++)
        #pragma unroll
        for (int ot = 0; ot < 4; ot++) acc[jt][ot] = z4;

    for (int ky = 0; ky < 3; ky++) {
        const int ri = i + ky - 1;
        for (int t = tid; t < 132 * 16; t += 256) {
            int col = t >> 4, c8 = t & 15;
            int nj = j0 - 1 + col;
            int4 pk = make_int4(0, 0, 0, 0);
            if (ri >= 0 && ri < LL && nj >= 0 && nj < WW) {
                int mp = (b * LL + ri) * WW + nj;
                if (mask[mp] == 0) pk = *(const int4*)(inB + (size_t)mp * DD + c8 * 8);
            }
            *(int4*)(&s_a[col][c8 * 8]) = pk;
        }
        {
            const int kb = ky * 384;
            #pragma unroll
            for (int it = 0; it < 2; it++) {
                int idx = it * 256 + tid, o = idx >> 2, q = idx & 3;
                *(int4*)(&s_b[0][o][q * 8]) = *(const int4*)(Wt + (size_t)o * 1152 + kb + q * 8);
            }
        }
        __syncthreads();

        for (int s = 0; s < 12; s++) {
            if (s < 11) {
                const int kb = ky * 384 + (s + 1) * 32;
                const int bufn = (s + 1) & 1;
                #pragma unroll
                for (int it = 0; it < 2; it++) {
                    int idx = it * 256 + tid, o = idx >> 2, q = idx & 3;
                    *(int4*)(&s_b[bufn][o][q * 8]) = *(const int4*)(Wt + (size_t)o * 1152 + kb + q * 8);
                }
            }
            const int kx = s >> 2;
            const int c0 = (s & 3) * 32 + lgp * 8;
            const int buf = s & 1;
            bf16x8 af[4], bfr[4];
            #pragma unroll
            for (int jt = 0; jt < 4; jt++) {
                int col = wr * 64 + jt * 16 + lrn + kx;
                af[jt] = *(const bf16x8*)(&s_a[col][c0]);
            }
            #pragma unroll
            for (int ot = 0; ot < 4; ot++) {
                int o = wc * 64 + ot * 16 + lrn;
                bfr[ot] = *(const bf16x8*)(&s_b[buf][o][lgp * 8]);
            }
            #pragma unroll
            for (int jt = 0; jt < 4; jt++)
                #pragma unroll
                for (int ot = 0; ot < 4; ot++)
                    acc[jt][ot] = __builtin_amdgcn_mfma_f32_16x16x32_bf16(af[jt], bfr[ot], acc[jt][ot], 0, 0, 0);
            __syncthreads();
        }
    }

    if (EPI == 0) {
        // GELU -> stage bf16 in s_a (dead now) -> coalesced store
        #pragma unroll
        for (int jt = 0; jt < 4; jt++) {
            #pragma unroll
            for (int r4 = 0; r4 < 4; r4++) {
                int jl = wr * 64 + jt * 16 + lgp * 4 + r4;
                #pragma unroll
                for (int ot = 0; ot < 4; ot++) {
                    int o = wc * 64 + ot * 16 + lrn;
                    float a = acc[jt][ot][r4];
                    float y = 0.5f * a * (1.f + erff(a * 0.70710678118654752f));
                    s_a[jl][o] = f2bf(y);
                }
            }
        }
        __syncthreads();
        #pragma unroll
        for (int it = 0; it < 8; it++) {
            int idx = it * 256 + tid;
            int p = idx >> 4, c8 = idx & 15;
            int j = j0 + p;
            if (j < WW) {
                size_t gp = (size_t)((b * LL + i) * WW + j) * DD;
                *(uint4*)(outB + gp + c8 * 8) = *(const uint4*)(&s_a[p][c8 * 8]);
            }
        }
    } else {
        float g2v[4], b2v[4];
        #pragma unroll
        for (int ot = 0; ot < 4; ot++) {
            int o = wc * 64 + ot * 16 + lrn;
            g2v[ot] = g2[o]; b2v[ot] = b2[o];
        }
        #pragma unroll
        for (int jt = 0; jt < 4; jt++) {
            #pragma unroll
            for (int r4 = 0; r4 < 4; r4++) {
                int jl = wr * 64 + jt * 16 + lgp * 4 + r4;
                int j = j0 + jl;
                float s1 = 0.f, s2 = 0.f;
                if (j < WW) {
                    size_t gp = (size_t)((b * LL + i) * WW + j) * DD;
                    #pragma unroll
                    for (int ot = 0; ot < 4; ot++) {
                        int o = wc * 64 + ot * 16 + lrn;
                        float v = acc[jt][ot][r4] + vb[gp + o];
                        acc[jt][ot][r4] = v;
                        s1 += v; s2 += v * v;
                    }
                }
                #pragma unroll
                for (int off = 1; off < 16; off <<= 1) {
                    s1 += __shfl_xor(s1, off);
                    s2 += __shfl_xor(s2, off);
                }
                if (lrn == 0) { redS[jl][wc] = s1; redQ[jl][wc] = s2; }
            }
        }
        __syncthreads();
        #pragma unroll
        for (int jt = 0; jt < 4; jt++) {
            #pragma unroll
            for (int r4 = 0; r4 < 4; r4++) {
                int jl = wr * 64 + jt * 16 + lgp * 4 + r4;
                int j = j0 + jl;
                if (j >= WW) continue;
                float mu = (redS[jl][0] + redS[jl][1]) * 0.0078125f;
                float q  = (redQ[jl][0] + redQ[jl][1]) * 0.0078125f;
                float inv = rsqrtf(q - mu * mu + 1e-5f);
                size_t gp = (size_t)((b * LL + i) * WW + j) * DD;
                #pragma unroll
                for (int ot = 0; ot < 4; ot++) {
                    int o = wc * 64 + ot * 16 + lrn;
                    outF[gp + o] = (acc[jt][ot][r4] - mu) * inv * g2v[ot] + b2v[ot];
                }
            }
        }
    }
}

extern "C" void kernel_launch(void* const* d_in, const int* in_sizes, int n_in,
                              void* d_out, int out_size, void* d_ws, size_t ws_size,
                              hipStream_t stream)
{
    (void)in_sizes; (void)n_in; (void)out_size; (void)ws_size;
    const float* x    = (const float*)d_in[0];
    const int*   mask = (const int*)d_in[1];
    const float* pe   = (const float*)d_in[2];
    const float* hW   = (const float*)d_in[3];
    const float* hb   = (const float*)d_in[4];
    const float* vW   = (const float*)d_in[5];
    const float* vbias= (const float*)d_in[6];
    const float* dw   = (const float*)d_in[7];
    const float* db   = (const float*)d_in[8];
    const float* g1   = (const float*)d_in[9];
    const float* b1   = (const float*)d_in[10];
    const float* w1   = (const float*)d_in[11];
    const float* w2   = (const float*)d_in[12];
    const float* g2   = (const float*)d_in[13];
    const float* b2   = (const float*)d_in[14];
    float* out = (float*)d_out;

    char* ws = (char*)d_ws;
    float* sintab = (float*)(ws + 0);            // 65536 B
    float* costab = (float*)(ws + 65536);        // 65536 B
    float* rvbuf  = (float*)(ws + 131072);       // 2048 B
    ushort_t* hWb = (ushort_t*)(ws + 143360);    // 98304 B
    ushort_t* vWb = (ushort_t*)(ws + 241664);    // 98304 B
    ushort_t* dwb = (ushort_t*)(ws + 339968);    // 65536 B
    ushort_t* Wt1 = (ushort_t*)(ws + 405504);    // 294912 B
    ushort_t* Wt2 = (ushort_t*)(ws + 700416);    // 294912 B

    const size_t R0 = 2097152;
    ushort_t* Qb = (ushort_t*)(ws + R0);                      // 33,292,800 B
    ushort_t* Kb = (ushort_t*)(ws + R0 + 33292800);           // 33,292,800 B
    ushort_t* Vt = (ushort_t*)(ws + R0 + 66585600);           // 33,423,360 B (128*510*256)
    float*    C  = (float*)(ws + R0);                         // 66,585,600 B (overlaps Qb+Kb, dead)
    ushort_t* Cb = (ushort_t*)(ws + R0 + 66585600);           // 33,292,800 B (overlaps Vt, dead)
    ushort_t* hvb = (ushort_t*)(ws + 102760448);              // 33,292,800 B
    ushort_t* vvb = (ushort_t*)(ws + 136314880);              // 33,292,800 B
    ushort_t* c1b = vvb;                                      // reuse after dense

    k_tables<<<1, 256, 0, stream>>>(mask, sintab, costab, rvbuf);
    k_wconv<<<1152, 256, 0, stream>>>(w1, w2, Wt1, Wt2);
    k_wmisc<<<192, 256, 0, stream>>>(hW, vW, dw, hWb, vWb, dwb);

    k_qkvm<0><<<1017, 256, 0, stream>>>(x, pe, hWb, hb, sintab, costab, Qb, Kb, Vt);
    k_attn2<<<dim3(4, RR), 256, 0, stream>>>(Qb, Kb, Vt, mask, hvb);
    k_qkvm<1><<<1017, 256, 0, stream>>>(x, pe, vWb, vbias, sintab, costab, Qb, Kb, Vt);
    k_attn2<<<dim3(4, RR), 256, 0, stream>>>(Qb, Kb, Vt, mask, vvb);

    k_dense2<<<1017, 256, 0, stream>>>(hvb, vvb, dwb, db, x, pe, rvbuf, g1, b1, C, Cb);
    k_convm<0><<<dim3(2, RR), 256, 0, stream>>>(Cb, mask, Wt1, nullptr, nullptr, nullptr, c1b, nullptr);
    k_convm<1><<<dim3(2, RR), 256, 0, stream>>>(c1b, mask, Wt2, C, g2, b2, nullptr, out);
}

// Round 5
// 566.206 us; speedup vs baseline: 16.1830x; 1.1080x over previous
//
#include <hip/hip_runtime.h>
#include <hip/hip_bf16.h>
#include <math.h>

constexpr int BSZ = 2;
constexpr int LL  = 255;
constexpr int WW  = 255;
constexpr int DD  = 128;
constexpr int RR  = BSZ * LL;     // 510 rows
constexpr int GG  = RR * WW;      // 130050 positions

typedef __attribute__((ext_vector_type(8))) short bf16x8;
typedef __attribute__((ext_vector_type(4))) float f32x4;
typedef unsigned short ushort_t;

__device__ __forceinline__ float clip1k(float v){ return fminf(fmaxf(v, -1000.f), 1000.f); }
__device__ __forceinline__ float clipT(float v){ return fminf(fmaxf(v, -10000.f), 10000.f); }
__device__ __forceinline__ unsigned short f2bf(float f){
    unsigned int u = __float_as_uint(f);
    unsigned int r = u + 0x7fffu + ((u >> 16) & 1u);
    return (unsigned short)(r >> 16);
}
__device__ __forceinline__ float bf2f(ushort_t h){
    return __uint_as_float(((unsigned)h) << 16);
}

// ---------------- tables: parallel row_valid + rotary tables -------------------------------
__global__ __launch_bounds__(64) void k_tables(const int* __restrict__ mask,
                                               float* __restrict__ sintab,
                                               float* __restrict__ costab,
                                               float* __restrict__ rv)
{
    int bid = blockIdx.x, lane = threadIdx.x;
    if (bid < RR) {
        const int* mr = mask + bid * WW;
        int s = 0;
        for (int j = lane; j < WW; j += 64) s += mr[j];
        #pragma unroll
        for (int off = 32; off > 0; off >>= 1) s += __shfl_xor(s, off);
        if (lane == 0) rv[bid] = (s != WW) ? 1.f : 0.f;
    } else {
        int base = (bid - RR) * 256;
        for (int k = 0; k < 4; k++) {
            int idx = base + k * 64 + lane;
            if (idx < WW * 64) {
                int p = idx >> 6, t = idx & 63;
                double freq = exp((double)t * (-9.210340371976184 / 64.0));
                double a = (double)p * freq;
                sintab[idx] = (float)sin(a);
                costab[idx] = (float)cos(a);
            }
        }
    }
}

// ---------------- conv weight transpose to bf16 [o][ky*384+kx*128+c] ----------------------
__global__ __launch_bounds__(256) void k_wconv(const float* __restrict__ w1,
                                               const float* __restrict__ w2,
                                               ushort_t* __restrict__ Wt1,
                                               ushort_t* __restrict__ Wt2)
{
    int idx = blockIdx.x * 256 + threadIdx.x;
    if (idx >= 2 * 147456) return;
    int buf = idx / 147456, rem = idx % 147456;
    int o = rem / 1152, k = rem % 1152;
    int ky = k / 384, kx = (k % 384) / 128, c = k % 128;
    const float* w = buf ? w2 : w1;
    float v = w[((o * 128 + c) * 3 + ky) * 3 + kx];
    (buf ? Wt2 : Wt1)[rem] = f2bf(v);
}

// ---------------- misc weight bf16 converts ------------------------------------------------
__global__ __launch_bounds__(256) void k_wmisc(const float* __restrict__ hW,
                                               const float* __restrict__ vW,
                                               const float* __restrict__ dw,
                                               ushort_t* __restrict__ hWb,
                                               ushort_t* __restrict__ vWb,
                                               ushort_t* __restrict__ dwb)
{
    int idx = blockIdx.x * 256 + threadIdx.x;
    if (idx < 49152) { hWb[idx] = f2bf(hW[idx]); vWb[idx] = f2bf(vW[idx]); }
    if (idx < 32768) dwb[idx] = f2bf(dw[idx]);
}

// ---------------- MFMA QKV projection (+clip, +rotary, V transposed) -----------------------
template <int BRANCH>
__global__ __launch_bounds__(256, 2) void k_qkvm(const float* __restrict__ x,
                                                 const float* __restrict__ pe,
                                                 const ushort_t* __restrict__ Wb,
                                                 const float* __restrict__ bias,
                                                 const float* __restrict__ sintab,
                                                 const float* __restrict__ costab,
                                                 ushort_t* __restrict__ Qb,
                                                 ushort_t* __restrict__ Kb,
                                                 ushort_t* __restrict__ Vt)
{
    __shared__ ushort_t xs[128][136];
    __shared__ ushort_t os[128][136];   // output staging (coalesced global stores)
    const int tid = threadIdx.x;
    const int l = tid & 63, w = tid >> 6;
    const int l15 = l & 15, l4g = l >> 4;
    const int wr = w & 1, wc = w >> 1;
    const int tile0 = blockIdx.x * 128;

    // stage X' tile (clip + pos-embed, branch gather), bf16
    for (int it = 0; it < 8; it++) {
        int idx = it * 256 + tid;
        int p = idx >> 4, c8 = idx & 15;
        int gpos = tile0 + p;
        uint4 pk = make_uint4(0u, 0u, 0u, 0u);
        if (gpos < GG) {
            int j = gpos % 255;
            const float* src;
            int pidx;
            if (BRANCH == 0) {
                src = x + (size_t)gpos * DD + c8 * 8;
                pidx = (j < 127) ? 0 : 1;
            } else {
                int b = gpos / (LL * WW);
                int rem = gpos - b * (LL * WW);
                int i = rem / WW;
                int ri = (i + j + 128) % 255;
                int cj = 254 - j;
                src = x + (size_t)((b * LL + ri) * WW + cj) * DD + c8 * 8;
                pidx = (j <= 127) ? 1 : 0;
            }
            float4 a0 = *(const float4*)src;
            float4 a1 = *(const float4*)(src + 4);
            float4 p0 = *(const float4*)(pe + pidx * DD + c8 * 8);
            float4 p1 = *(const float4*)(pe + pidx * DD + c8 * 8 + 4);
            float e0 = clip1k(a0.x) + p0.x, e1 = clip1k(a0.y) + p0.y;
            float e2 = clip1k(a0.z) + p0.z, e3 = clip1k(a0.w) + p0.w;
            float e4 = clip1k(a1.x) + p1.x, e5 = clip1k(a1.y) + p1.y;
            float e6 = clip1k(a1.z) + p1.z, e7 = clip1k(a1.w) + p1.w;
            pk.x = f2bf(e0) | ((unsigned)f2bf(e1) << 16);
            pk.y = f2bf(e2) | ((unsigned)f2bf(e3) << 16);
            pk.z = f2bf(e4) | ((unsigned)f2bf(e5) << 16);
            pk.w = f2bf(e6) | ((unsigned)f2bf(e7) << 16);
        }
        *(uint4*)(&xs[p][c8 * 8]) = pk;
    }
    __syncthreads();

    for (int part = 0; part < 3; part++) {
        f32x4 acc[4][4];
        const f32x4 z4 = {0.f, 0.f, 0.f, 0.f};
        #pragma unroll
        for (int mt = 0; mt < 4; mt++)
            #pragma unroll
            for (int nt = 0; nt < 4; nt++) acc[mt][nt] = z4;

        #pragma unroll
        for (int kk = 0; kk < 4; kk++) {
            bf16x8 af[4], bf[4];
            #pragma unroll
            for (int mt = 0; mt < 4; mt++)
                af[mt] = *(const bf16x8*)(Wb + (size_t)(part * 128 + wr * 64 + mt * 16 + l15) * 128 + kk * 32 + l4g * 8);
            #pragma unroll
            for (int nt = 0; nt < 4; nt++)
                bf[nt] = *(const bf16x8*)(&xs[wc * 64 + nt * 16 + l15][kk * 32 + l4g * 8]);
            #pragma unroll
            for (int mt = 0; mt < 4; mt++)
                #pragma unroll
                for (int nt = 0; nt < 4; nt++)
                    acc[mt][nt] = __builtin_amdgcn_mfma_f32_16x16x32_bf16(af[mt], bf[nt], acc[mt][nt], 0, 0, 0);
        }

        // epilogue: bias + clip + rotary(Q,K) / LDS transpose (V); all -> os staging
        #pragma unroll
        for (int mt = 0; mt < 4; mt++) {
            int obase = wr * 64 + mt * 16 + l4g * 4;
            float4 bv = *(const float4*)(bias + part * 128 + obase);
            #pragma unroll
            for (int nt = 0; nt < 4; nt++) {
                int pl = wc * 64 + nt * 16 + l15;
                int gpos = tile0 + pl;
                int j = (gpos < GG) ? (gpos % 255) : 0;
                float v0 = clipT(acc[mt][nt][0] + bv.x);
                float v1 = clipT(acc[mt][nt][1] + bv.y);
                float v2 = clipT(acc[mt][nt][2] + bv.z);
                float v3 = clipT(acc[mt][nt][3] + bv.w);
                if (part < 2) {
                    int t0 = obase >> 1;
                    float cs0 = costab[j * 64 + t0],     sn0 = sintab[j * 64 + t0];
                    float cs1 = costab[j * 64 + t0 + 1], sn1 = sintab[j * 64 + t0 + 1];
                    float r0 = v0 * cs0 - v1 * sn0;
                    float r1 = v1 * cs0 + v0 * sn0;
                    float r2 = v2 * cs1 - v3 * sn1;
                    float r3 = v3 * cs1 + v2 * sn1;
                    *(unsigned*)(&os[pl][obase])     = f2bf(r0) | ((unsigned)f2bf(r1) << 16);
                    *(unsigned*)(&os[pl][obase + 2]) = f2bf(r2) | ((unsigned)f2bf(r3) << 16);
                } else {
                    os[obase + 0][pl] = f2bf(v0);
                    os[obase + 1][pl] = f2bf(v1);
                    os[obase + 2][pl] = f2bf(v2);
                    os[obase + 3][pl] = f2bf(v3);
                }
            }
        }
        __syncthreads();

        if (part < 2) {
            ushort_t* dst = (part == 0) ? Qb : Kb;
            #pragma unroll
            for (int it = 0; it < 8; it++) {
                int idx = it * 256 + tid;
                int p = idx >> 4, c8 = idx & 15;
                int gpos = tile0 + p;
                if (gpos < GG) *(uint4*)(dst + (size_t)gpos * 128 + c8 * 8) = *(const uint4*)(&os[p][c8 * 8]);
            }
        } else {
            for (int it = 0; it < 64; it++) {
                int idx = it * 256 + tid;
                int d = idx >> 7, p = idx & 127;
                int gpos = tile0 + p;
                if (gpos < GG) {
                    int rg = gpos / 255, j = gpos - rg * 255;
                    Vt[((size_t)d * 510 + rg) * 256 + j] = os[d][p];
                }
            }
        }
        __syncthreads();
    }
}

// ---------------- MFMA attention, register softmax -----------------------------------------
__global__ __launch_bounds__(256, 2) void k_attn2(const ushort_t* __restrict__ Qb,
                                                  const ushort_t* __restrict__ Kb,
                                                  const ushort_t* __restrict__ Vt,
                                                  const int* __restrict__ mask,
                                                  ushort_t* __restrict__ outO)
{
    __shared__ ushort_t pb[64][264];   // P bf16; later O staging
    __shared__ float redM[64][4];
    __shared__ float redS[64][4];

    const int tid = threadIdx.x;
    const int l = tid & 63, w = tid >> 6;
    const int l15 = l & 15, l4g = l >> 4;
    const int qt = blockIdx.x, rg = blockIdx.y;
    const int q0 = qt * 64;
    const size_t rowbase = (size_t)rg * 255;
    const float iscale = 0.0883883476483184f;    // 1/sqrt(128)

    // ---- QK^T ----
    const bf16x8 zf = {0, 0, 0, 0, 0, 0, 0, 0};
    f32x4 acc[4][4];
    const f32x4 z4 = {0.f, 0.f, 0.f, 0.f};
    #pragma unroll
    for (int mt = 0; mt < 4; mt++)
        #pragma unroll
        for (int nt = 0; nt < 4; nt++) acc[mt][nt] = z4;

    #pragma unroll
    for (int kk = 0; kk < 4; kk++) {
        bf16x8 qf[4], bf[4];
        #pragma unroll
        for (int mt = 0; mt < 4; mt++) {
            int q = q0 + mt * 16 + l15;
            qf[mt] = (q < 255) ? *(const bf16x8*)(Qb + (rowbase + q) * 128 + kk * 32 + l4g * 8) : zf;
        }
        #pragma unroll
        for (int nt = 0; nt < 4; nt++) {
            int kpos = w * 64 + nt * 16 + l15;
            bf[nt] = (kpos < 255) ? *(const bf16x8*)(Kb + (rowbase + kpos) * 128 + kk * 32 + l4g * 8) : zf;
        }
        #pragma unroll
        for (int mt = 0; mt < 4; mt++)
            #pragma unroll
            for (int nt = 0; nt < 4; nt++)
                acc[mt][nt] = __builtin_amdgcn_mfma_f32_16x16x32_bf16(qf[mt], bf[nt], acc[mt][nt], 0, 0, 0);
    }

    // ---- scale + clip + additive mask (in-register) ----
    float madd[4]; int keep[4];
    #pragma unroll
    for (int nt = 0; nt < 4; nt++) {
        int j = w * 64 + nt * 16 + l15;
        bool jv = (j < 255);
        int mv = jv ? mask[rowbase + j] : 1;
        madd[nt] = (mv > 0) ? -10000.f : 0.f;
        keep[nt] = (jv && mv == 0) ? 1 : 0;
        #pragma unroll
        for (int mt = 0; mt < 4; mt++)
            #pragma unroll
            for (int r = 0; r < 4; r++) {
                float s = jv ? (clipT(acc[mt][nt][r] * iscale) + madd[nt]) : -1e38f;
                acc[mt][nt][r] = s;
            }
    }

    // ---- row max: in-lane over nt, shfl over l15, LDS over waves ----
    float pm[4][4];
    #pragma unroll
    for (int mt = 0; mt < 4; mt++)
        #pragma unroll
        for (int r = 0; r < 4; r++) {
            float v = fmaxf(fmaxf(acc[mt][0][r], acc[mt][1][r]), fmaxf(acc[mt][2][r], acc[mt][3][r]));
            pm[mt][r] = v;
        }
    #pragma unroll
    for (int off = 1; off < 16; off <<= 1)
        #pragma unroll
        for (int mt = 0; mt < 4; mt++)
            #pragma unroll
            for (int r = 0; r < 4; r++)
                pm[mt][r] = fmaxf(pm[mt][r], __shfl_xor(pm[mt][r], off));
    if (l15 == 0) {
        #pragma unroll
        for (int mt = 0; mt < 4; mt++)
            #pragma unroll
            for (int r = 0; r < 4; r++)
                redM[mt * 16 + l4g * 4 + r][w] = pm[mt][r];
    }
    __syncthreads();
    float m[4][4];
    #pragma unroll
    for (int mt = 0; mt < 4; mt++)
        #pragma unroll
        for (int r = 0; r < 4; r++) {
            int q = mt * 16 + l4g * 4 + r;
            m[mt][r] = fmaxf(fmaxf(redM[q][0], redM[q][1]), fmaxf(redM[q][2], redM[q][3]));
        }

    // ---- exp + row sum (denominator includes masked terms, like reference) ----
    float ps[4][4];
    #pragma unroll
    for (int mt = 0; mt < 4; mt++)
        #pragma unroll
        for (int r = 0; r < 4; r++) {
            float s = 0.f;
            #pragma unroll
            for (int nt = 0; nt < 4; nt++) {
                float e = __expf(acc[mt][nt][r] - m[mt][r]);
                s += e;
                acc[mt][nt][r] = keep[nt] ? e : 0.f;
            }
            ps[mt][r] = s;
        }
    #pragma unroll
    for (int off = 1; off < 16; off <<= 1)
        #pragma unroll
        for (int mt = 0; mt < 4; mt++)
            #pragma unroll
            for (int r = 0; r < 4; r++)
                ps[mt][r] += __shfl_xor(ps[mt][r], off);
    if (l15 == 0) {
        #pragma unroll
        for (int mt = 0; mt < 4; mt++)
            #pragma unroll
            for (int r = 0; r < 4; r++)
                redS[mt * 16 + l4g * 4 + r][w] = ps[mt][r];
    }
    __syncthreads();

    // ---- write P bf16 to LDS ----
    #pragma unroll
    for (int mt = 0; mt < 4; mt++)
        #pragma unroll
        for (int r = 0; r < 4; r++) {
            int q = mt * 16 + l4g * 4 + r;
            float inv = 1.f / (redS[q][0] + redS[q][1] + redS[q][2] + redS[q][3]);
            #pragma unroll
            for (int nt = 0; nt < 4; nt++) {
                int j = w * 64 + nt * 16 + l15;
                pb[q][j] = f2bf(acc[mt][nt][r] * inv);
            }
        }
    __syncthreads();

    // ---- AV ----
    f32x4 av[4][2];
    #pragma unroll
    for (int mt = 0; mt < 4; mt++) { av[mt][0] = z4; av[mt][1] = z4; }
    #pragma unroll
    for (int kk = 0; kk < 8; kk++) {
        bf16x8 pa[4], vf[2];
        #pragma unroll
        for (int mt = 0; mt < 4; mt++)
            pa[mt] = *(const bf16x8*)(&pb[mt * 16 + l15][kk * 32 + l4g * 8]);
        #pragma unroll
        for (int nt = 0; nt < 2; nt++) {
            int d = w * 32 + nt * 16 + l15;
            vf[nt] = *(const bf16x8*)(Vt + ((size_t)d * 510 + rg) * 256 + kk * 32 + l4g * 8);
        }
        #pragma unroll
        for (int mt = 0; mt < 4; mt++)
            #pragma unroll
            for (int nt = 0; nt < 2; nt++)
                av[mt][nt] = __builtin_amdgcn_mfma_f32_16x16x32_bf16(pa[mt], vf[nt], av[mt][nt], 0, 0, 0);
    }

    // ---- stage O in LDS (overwrites pb), then coalesced store ----
    __syncthreads();
    ushort_t* osA = (ushort_t*)pb;   // [64][136]
    #pragma unroll
    for (int mt = 0; mt < 4; mt++) {
        #pragma unroll
        for (int r = 0; r < 4; r++) {
            int ql = mt * 16 + l4g * 4 + r;
            #pragma unroll
            for (int nt = 0; nt < 2; nt++) {
                int d = w * 32 + nt * 16 + l15;
                osA[ql * 136 + d] = f2bf(av[mt][nt][r]);
            }
        }
    }
    __syncthreads();
    #pragma unroll
    for (int it = 0; it < 4; it++) {
        int idx = it * 256 + tid;
        int p = idx >> 4, c8 = idx & 15;
        int q = q0 + p;
        if (q < 255) *(uint4*)(outO + (rowbase + q) * 128 + c8 * 8) = *(const uint4*)(&osA[p * 136 + c8 * 8]);
    }
}

// ---------------- MFMA dense (concat 256 -> 128) + rv + residual + LN1 (bf16 out) ----------
__global__ __launch_bounds__(256, 2) void k_dense2(const ushort_t* __restrict__ hv,
                                                   const ushort_t* __restrict__ vv,
                                                   const ushort_t* __restrict__ dwb,
                                                   const float* __restrict__ db,
                                                   const float* __restrict__ x,
                                                   const float* __restrict__ pe,
                                                   const float* __restrict__ rv,
                                                   const float* __restrict__ g1,
                                                   const float* __restrict__ b1,
                                                   ushort_t* __restrict__ Cb)
{
    __shared__ float redS[128][2], redQ[128][2];
    __shared__ ushort_t os[128][136];
    const int tid = threadIdx.x;
    const int l = tid & 63, w = tid >> 6;
    const int l15 = l & 15, l4g = l >> 4;
    const int wr = w & 1, wc = w >> 1;
    const int tile0 = blockIdx.x * 128;

    f32x4 acc[4][4];
    const f32x4 z4 = {0.f, 0.f, 0.f, 0.f};
    #pragma unroll
    for (int mt = 0; mt < 4; mt++)
        #pragma unroll
        for (int nt = 0; nt < 4; nt++) acc[mt][nt] = z4;

    #pragma unroll
    for (int kk = 0; kk < 8; kk++) {
        bf16x8 af[4], bf[4];
        #pragma unroll
        for (int mt = 0; mt < 4; mt++) {
            int gpos = tile0 + wr * 64 + mt * 16 + l15;
            if (gpos >= GG) gpos = GG - 1;
            const ushort_t* srcp = (kk < 4) ? (hv + (size_t)gpos * 128 + kk * 32 + l4g * 8)
                                            : (vv + (size_t)gpos * 128 + (kk - 4) * 32 + l4g * 8);
            af[mt] = *(const bf16x8*)srcp;
        }
        #pragma unroll
        for (int nt = 0; nt < 4; nt++) {
            int o = wc * 64 + nt * 16 + l15;
            bf[nt] = *(const bf16x8*)(dwb + (size_t)o * 256 + kk * 32 + l4g * 8);
        }
        #pragma unroll
        for (int mt = 0; mt < 4; mt++)
            #pragma unroll
            for (int nt = 0; nt < 4; nt++)
                acc[mt][nt] = __builtin_amdgcn_mfma_f32_16x16x32_bf16(af[mt], bf[nt], acc[mt][nt], 0, 0, 0);
    }

    // epilogue: val = (acc + db)*rv + resid; LN over 128 channels
    #pragma unroll
    for (int mt = 0; mt < 4; mt++) {
        #pragma unroll
        for (int r = 0; r < 4; r++) {
            int row = wr * 64 + mt * 16 + l4g * 4 + r;
            int gpos = tile0 + row;
            bool valid = (gpos < GG);
            int rg = valid ? gpos / 255 : 0;
            int j = gpos - rg * 255;
            float rvv = valid ? rv[rg] : 0.f;
            int pidx = (j < 127) ? 0 : 1;
            float s1 = 0.f, s2 = 0.f;
            #pragma unroll
            for (int nt = 0; nt < 4; nt++) {
                int o = wc * 64 + nt * 16 + l15;
                float resid = 0.f;
                if (valid) resid = clip1k(x[(size_t)gpos * 128 + o]) + pe[pidx * 128 + o];
                float v = (acc[mt][nt][r] + db[o]) * rvv + resid;
                acc[mt][nt][r] = v;
                s1 += v; s2 += v * v;
            }
            s1 += __shfl_xor(s1, 1); s2 += __shfl_xor(s2, 1);
            s1 += __shfl_xor(s1, 2); s2 += __shfl_xor(s2, 2);
            s1 += __shfl_xor(s1, 4); s2 += __shfl_xor(s2, 4);
            s1 += __shfl_xor(s1, 8); s2 += __shfl_xor(s2, 8);
            if (l15 == 0) { redS[row][wc] = s1; redQ[row][wc] = s2; }
        }
    }
    __syncthreads();
    #pragma unroll
    for (int mt = 0; mt < 4; mt++) {
        #pragma unroll
        for (int r = 0; r < 4; r++) {
            int row = wr * 64 + mt * 16 + l4g * 4 + r;
            int gpos = tile0 + row;
            if (gpos >= GG) continue;
            float mu = (redS[row][0] + redS[row][1]) * 0.0078125f;
            float q  = (redQ[row][0] + redQ[row][1]) * 0.0078125f;
            float inv = rsqrtf(q - mu * mu + 1e-5f);
            #pragma unroll
            for (int nt = 0; nt < 4; nt++) {
                int o = wc * 64 + nt * 16 + l15;
                float y = (acc[mt][nt][r] - mu) * inv * g1[o] + b1[o];
                os[row][o] = f2bf(y);
            }
        }
    }
    __syncthreads();
    #pragma unroll
    for (int it = 0; it < 8; it++) {
        int idx = it * 256 + tid;
        int p = idx >> 4, c8 = idx & 15;
        int gpos = tile0 + p;
        if (gpos < GG) *(uint4*)(Cb + (size_t)gpos * 128 + c8 * 8) = *(const uint4*)(&os[p][c8 * 8]);
    }
}

// ---------------- MFMA masked 3x3 conv (bf16 in). EPI 0: gelu->bf16. EPI 1: +vb(bf16),LN2 --
template <int EPI>
__global__ __launch_bounds__(256, 2) void k_convm(const ushort_t* __restrict__ inB,
                                                  const int* __restrict__ mask,
                                                  const ushort_t* __restrict__ Wt,
                                                  const ushort_t* __restrict__ vbB,
                                                  const float* __restrict__ g2,
                                                  const float* __restrict__ b2,
                                                  ushort_t* __restrict__ outB,
                                                  float* __restrict__ outF)
{
    __shared__ ushort_t s_a[132][136];
    __shared__ ushort_t s_b[2][128][40];
    __shared__ float redS[128][2], redQ[128][2];

    const int tid = threadIdx.x;
    const int l  = tid & 63, lrn = l & 15, lgp = l >> 4;
    const int w  = tid >> 6, wr = w & 1, wc = w >> 1;
    const int r  = blockIdx.y, b = r / LL, i = r % LL;
    const int j0 = blockIdx.x * 128;

    f32x4 acc[4][4];
    const f32x4 z4 = {0.f, 0.f, 0.f, 0.f};
    #pragma unroll
    for (int jt = 0; jt < 4; jt++)
        #pragma unroll
        for (int ot = 0; ot < 4; ot++) acc[jt][ot] = z4;

    for (int ky = 0; ky < 3; ky++) {
        const int ri = i + ky - 1;
        for (int t = tid; t < 132 * 16; t += 256) {
            int col = t >> 4, c8 = t & 15;
            int nj = j0 - 1 + col;
            int4 pk = make_int4(0, 0, 0, 0);
            if (ri >= 0 && ri < LL && nj >= 0 && nj < WW) {
                int mp = (b * LL + ri) * WW + nj;
                if (mask[mp] == 0) pk = *(const int4*)(inB + (size_t)mp * DD + c8 * 8);
            }
            *(int4*)(&s_a[col][c8 * 8]) = pk;
        }
        {
            const int kb = ky * 384;
            #pragma unroll
            for (int it = 0; it < 2; it++) {
                int idx = it * 256 + tid, o = idx >> 2, q = idx & 3;
                *(int4*)(&s_b[0][o][q * 8]) = *(const int4*)(Wt + (size_t)o * 1152 + kb + q * 8);
            }
        }
        __syncthreads();

        for (int s = 0; s < 12; s++) {
            if (s < 11) {
                const int kb = ky * 384 + (s + 1) * 32;
                const int bufn = (s + 1) & 1;
                #pragma unroll
                for (int it = 0; it < 2; it++) {
                    int idx = it * 256 + tid, o = idx >> 2, q = idx & 3;
                    *(int4*)(&s_b[bufn][o][q * 8]) = *(const int4*)(Wt + (size_t)o * 1152 + kb + q * 8);
                }
            }
            const int kx = s >> 2;
            const int c0 = (s & 3) * 32 + lgp * 8;
            const int buf = s & 1;
            bf16x8 af[4], bfr[4];
            #pragma unroll
            for (int jt = 0; jt < 4; jt++) {
                int col = wr * 64 + jt * 16 + lrn + kx;
                af[jt] = *(const bf16x8*)(&s_a[col][c0]);
            }
            #pragma unroll
            for (int ot = 0; ot < 4; ot++) {
                int o = wc * 64 + ot * 16 + lrn;
                bfr[ot] = *(const bf16x8*)(&s_b[buf][o][lgp * 8]);
            }
            #pragma unroll
            for (int jt = 0; jt < 4; jt++)
                #pragma unroll
                for (int ot = 0; ot < 4; ot++)
                    acc[jt][ot] = __builtin_amdgcn_mfma_f32_16x16x32_bf16(af[jt], bfr[ot], acc[jt][ot], 0, 0, 0);
            __syncthreads();
        }
    }

    if (EPI == 0) {
        // GELU -> stage bf16 in s_a (dead now) -> coalesced store
        #pragma unroll
        for (int jt = 0; jt < 4; jt++) {
            #pragma unroll
            for (int r4 = 0; r4 < 4; r4++) {
                int jl = wr * 64 + jt * 16 + lgp * 4 + r4;
                #pragma unroll
                for (int ot = 0; ot < 4; ot++) {
                    int o = wc * 64 + ot * 16 + lrn;
                    float a = acc[jt][ot][r4];
                    float y = 0.5f * a * (1.f + erff(a * 0.70710678118654752f));
                    s_a[jl][o] = f2bf(y);
                }
            }
        }
        __syncthreads();
        #pragma unroll
        for (int it = 0; it < 8; it++) {
            int idx = it * 256 + tid;
            int p = idx >> 4, c8 = idx & 15;
            int j = j0 + p;
            if (j < WW) {
                size_t gp = (size_t)((b * LL + i) * WW + j) * DD;
                *(uint4*)(outB + gp + c8 * 8) = *(const uint4*)(&s_a[p][c8 * 8]);
            }
        }
    } else {
        // stage residual (bf16) coalesced into s_a
        #pragma unroll
        for (int it = 0; it < 8; it++) {
            int idx = it * 256 + tid;
            int p = idx >> 4, c8 = idx & 15;
            int j = j0 + p;
            uint4 v = make_uint4(0u, 0u, 0u, 0u);
            if (j < WW) v = *(const uint4*)(vbB + (size_t)((b * LL + i) * WW + j) * DD + c8 * 8);
            *(uint4*)(&s_a[p][c8 * 8]) = v;
        }
        __syncthreads();

        float g2v[4], b2v[4];
        #pragma unroll
        for (int ot = 0; ot < 4; ot++) {
            int o = wc * 64 + ot * 16 + lrn;
            g2v[ot] = g2[o]; b2v[ot] = b2[o];
        }
        #pragma unroll
        for (int jt = 0; jt < 4; jt++) {
            #pragma unroll
            for (int r4 = 0; r4 < 4; r4++) {
                int jl = wr * 64 + jt * 16 + lgp * 4 + r4;
                int j = j0 + jl;
                float s1 = 0.f, s2 = 0.f;
                if (j < WW) {
                    #pragma unroll
                    for (int ot = 0; ot < 4; ot++) {
                        int o = wc * 64 + ot * 16 + lrn;
                        float v = acc[jt][ot][r4] + bf2f(s_a[jl][o]);
                        acc[jt][ot][r4] = v;
                        s1 += v; s2 += v * v;
                    }
                }
                #pragma unroll
                for (int off = 1; off < 16; off <<= 1) {
                    s1 += __shfl_xor(s1, off);
                    s2 += __shfl_xor(s2, off);
                }
                if (lrn == 0) { redS[jl][wc] = s1; redQ[jl][wc] = s2; }
            }
        }
        __syncthreads();
        #pragma unroll
        for (int jt = 0; jt < 4; jt++) {
            #pragma unroll
            for (int r4 = 0; r4 < 4; r4++) {
                int jl = wr * 64 + jt * 16 + lgp * 4 + r4;
                int j = j0 + jl;
                if (j >= WW) continue;
                float mu = (redS[jl][0] + redS[jl][1]) * 0.0078125f;
                float q  = (redQ[jl][0] + redQ[jl][1]) * 0.0078125f;
                float inv = rsqrtf(q - mu * mu + 1e-5f);
                size_t gp = (size_t)((b * LL + i) * WW + j) * DD;
                #pragma unroll
                for (int ot = 0; ot < 4; ot++) {
                    int o = wc * 64 + ot * 16 + lrn;
                    outF[gp + o] = (acc[jt][ot][r4] - mu) * inv * g2v[ot] + b2v[ot];
                }
            }
        }
    }
}

extern "C" void kernel_launch(void* const* d_in, const int* in_sizes, int n_in,
                              void* d_out, int out_size, void* d_ws, size_t ws_size,
                              hipStream_t stream)
{
    (void)in_sizes; (void)n_in; (void)out_size; (void)ws_size;
    const float* x    = (const float*)d_in[0];
    const int*   mask = (const int*)d_in[1];
    const float* pe   = (const float*)d_in[2];
    const float* hW   = (const float*)d_in[3];
    const float* hb   = (const float*)d_in[4];
    const float* vW   = (const float*)d_in[5];
    const float* vbias= (const float*)d_in[6];
    const float* dw   = (const float*)d_in[7];
    const float* db   = (const float*)d_in[8];
    const float* g1   = (const float*)d_in[9];
    const float* b1   = (const float*)d_in[10];
    const float* w1   = (const float*)d_in[11];
    const float* w2   = (const float*)d_in[12];
    const float* g2   = (const float*)d_in[13];
    const float* b2   = (const float*)d_in[14];
    float* out = (float*)d_out;

    char* ws = (char*)d_ws;
    float* sintab = (float*)(ws + 0);            // 65536 B
    float* costab = (float*)(ws + 65536);        // 65536 B
    float* rvbuf  = (float*)(ws + 131072);       // 2048 B
    ushort_t* hWb = (ushort_t*)(ws + 143360);    // 98304 B
    ushort_t* vWb = (ushort_t*)(ws + 241664);    // 98304 B
    ushort_t* dwb = (ushort_t*)(ws + 339968);    // 65536 B
    ushort_t* Wt1 = (ushort_t*)(ws + 405504);    // 294912 B
    ushort_t* Wt2 = (ushort_t*)(ws + 700416);    // 294912 B

    const size_t R0 = 2097152;
    ushort_t* Qb = (ushort_t*)(ws + R0);                      // 33,292,800 B
    ushort_t* Kb = (ushort_t*)(ws + R0 + 33292800);           // 33,292,800 B
    ushort_t* Vt = (ushort_t*)(ws + R0 + 66585600);           // 33,423,360 B (128*510*256)
    ushort_t* Cb = (ushort_t*)(ws + R0 + 66585600);           // 33,292,800 B (overlaps Vt, dead by then)
    ushort_t* hvb = (ushort_t*)(ws + 102760448);              // 33,292,800 B
    ushort_t* vvb = (ushort_t*)(ws + 136314880);              // 33,292,800 B
    ushort_t* c1b = vvb;                                      // reuse after dense

    k_tables<<<RR + 64, 64, 0, stream>>>(mask, sintab, costab, rvbuf);
    k_wconv<<<1152, 256, 0, stream>>>(w1, w2, Wt1, Wt2);
    k_wmisc<<<192, 256, 0, stream>>>(hW, vW, dw, hWb, vWb, dwb);

    k_qkvm<0><<<1017, 256, 0, stream>>>(x, pe, hWb, hb, sintab, costab, Qb, Kb, Vt);
    k_attn2<<<dim3(4, RR), 256, 0, stream>>>(Qb, Kb, Vt, mask, hvb);
    k_qkvm<1><<<1017, 256, 0, stream>>>(x, pe, vWb, vbias, sintab, costab, Qb, Kb, Vt);
    k_attn2<<<dim3(4, RR), 256, 0, stream>>>(Qb, Kb, Vt, mask, vvb);

    k_dense2<<<1017, 256, 0, stream>>>(hvb, vvb, dwb, db, x, pe, rvbuf, g1, b1, Cb);
    k_convm<0><<<dim3(2, RR), 256, 0, stream>>>(Cb, mask, Wt1, nullptr, nullptr, nullptr, c1b, nullptr);
    k_convm<1><<<dim3(2, RR), 256, 0, stream>>>(c1b, mask, Wt2, Cb, g2, b2, nullptr, out);
}